// Round 5
// baseline (3344.813 us; speedup 1.0000x reference)
//
#include <hip/hip_runtime.h>
#include <hip/hip_fp16.h>

// B=256,S=256,T=32,H=512,E=128,V=1000,A=8,NT=80.
// Math: decoder is dead code (softmax shift-invariance over S) -> outputs are
// pa/pt tiled over T. Remaining: 256 serial LSTM steps + attention readout.
//
// Structure: 16 batch-groups x (16 rows, 16 wgs of 256 thr); each wg owns 128
// z-cols, Wh in registers (bf16), h hi/lo bf16 split (2 MFMAs ~ fp32), x-part
// precomputed (P = embed@Wi.T + b, fp32 gather).
// R1: __threadfence -> buffer_wbl2+inv nuked L2 every step. Fixed (2x).
// R2/R3: pinned 6.7us/step -> 8B atomic h-loads serialized. R4: pipelined
// coherent b128 loads -> 3.1us/step.
// R5 (this): per-WAVE flags (own-wave vmcnt drain, no pre-flag barrier),
// 2-deep pipelined asm poll by every wave (no post-poll barrier; 2 barriers
// per step total), fragment-ordered hbuf (hi/lo planes split at producer ->
// zero consumer unpack, b128 LDS writes, pad-80 LDS rows = 2-way-only banks).

#define Bv 256
#define Sv 256
#define Tv 32
#define Hv 512
#define KT 16          // k-tiles of 32 over K=512
#define GM 16          // batch rows per group
// hbuf chunk layout (global, per group, per parity): [chunk16][plane2][row16][col32] bf16
//   chunk stride 2048B, plane 1024B, row 64B. Total 32KB/parity.
// LDS staged copy adds row padding: row stride 80B, plane 1280B, chunk 2560B.
#define LCH 2560
#define LPL 1280
#define LRW 80

typedef __attribute__((ext_vector_type(8))) short bf16x8;
typedef __attribute__((ext_vector_type(4))) float f32x4;
typedef __attribute__((ext_vector_type(4))) unsigned uint4v;

__device__ __forceinline__ unsigned short f2bf(float x) {   // RNE fp32->bf16
  unsigned u = __builtin_bit_cast(unsigned, x);
  u += 0x7fffu + ((u >> 16) & 1u);
  return (unsigned short)(u >> 16);
}
__device__ __forceinline__ float bf2f(unsigned short h) {
  unsigned u = ((unsigned)h) << 16;
  return __builtin_bit_cast(float, u);
}
__device__ __forceinline__ float sigm(float x) { return 1.0f / (1.0f + __expf(-x)); }
__device__ __forceinline__ float tanh_fast(float x) {
  x = fminf(15.f, fmaxf(-15.f, x));
  float e = __expf(2.f * x);
  return (e - 1.f) / (e + 1.f);
}

// Coherent (device-scope) 16B load: bypasses L1/L2, pipelines like any vmem op.
__device__ __forceinline__ uint4v ld_b128_sys(const void* p) {
  uint4v r;
  asm volatile("global_load_dwordx4 %0, %1, off sc0 sc1" : "=v"(r) : "v"(p));
  return r;
}

// ---- P[v][n] = sum_k embed[v][k]*Wi[n][k] + be[n], fp32. 250 blocks x 4 tokens.
__global__ __launch_bounds__(256)
void build_P(const float* __restrict__ embed, const float* __restrict__ Wi,
             const float* __restrict__ be, float* __restrict__ P)
{
  __shared__ float ev[4][128];
  const int tid = threadIdx.x;
  const int v0  = blockIdx.x * 4;
#pragma unroll
  for (int i = 0; i < 2; ++i) {
    int e = tid + i * 256;
    ev[e >> 7][e & 127] = embed[(v0 + (e >> 7)) * 128 + (e & 127)];
  }
  __syncthreads();
#pragma unroll 1
  for (int cc = 0; cc < 8; ++cc) {
    int n = cc * 256 + tid;
    float b = be[n];
    float a0 = b, a1 = b, a2 = b, a3 = b;
    const f32x4* w = (const f32x4*)(Wi + n * 128);
#pragma unroll
    for (int k4 = 0; k4 < 32; ++k4) {
      f32x4 wv = w[k4];
#pragma unroll
      for (int j = 0; j < 4; ++j) {
        float wj = wv[j];
        int k = k4 * 4 + j;
        a0 += wj * ev[0][k]; a1 += wj * ev[1][k];
        a2 += wj * ev[2][k]; a3 += wj * ev[3][k];
      }
    }
    P[(size_t)(v0 + 0) * 2048 + n] = a0;
    P[(size_t)(v0 + 1) * 2048 + n] = a1;
    P[(size_t)(v0 + 2) * 2048 + n] = a2;
    P[(size_t)(v0 + 3) * 2048 + n] = a3;
  }
}

// flags: per group, 64 flags (chunk cb x wave w) = 256B line region.
__global__ __launch_bounds__(256, 1)
void lstm_enc(const int* __restrict__ enc_in, const float* __restrict__ P,
              const float* __restrict__ Wh,
              unsigned* __restrict__ flags, char* __restrict__ hbuf,
              __half* __restrict__ enc_out)
{
  __shared__ __attribute__((aligned(16))) char Asg[16 * LCH];  // 40KB staged A (hi/lo planes)
  __shared__ float zbuf[4][GM][37];

  const int tid  = threadIdx.x;
  const int wg   = blockIdx.x;
  const int g    = wg & 15;   // group (members share wg%8 -> same XCD heuristically; perf only)
  const int cb   = wg >> 4;   // column block: owns z-cols [q*512 + cb*32, +32) per gate q
  const int wave = tid >> 6;  // wave == gate q (0=i,1=f,2=g,3=o)
  const int lane = tid & 63;
  const int m16  = lane & 15;
  const int qd   = lane >> 4;

  // ---- Wh fragments in registers: lane holds W'[n][k] for
  // n = wave*512 + cb*32 + nt*16 + m16, k = kt*32 + qd*8 + j (j=0..7).
  bf16x8 wf[KT][2];
#pragma unroll
  for (int kt = 0; kt < KT; ++kt) {
#pragma unroll
    for (int nt = 0; nt < 2; ++nt) {
      int n  = wave * 512 + cb * 32 + nt * 16 + m16;
      int k0 = kt * 32 + qd * 8;
      const float* src = Wh + (size_t)n * Hv + k0;
      f32x4 f0 = *(const f32x4*)(src);
      f32x4 f1 = *(const f32x4*)(src + 4);
      bf16x8 w;
      w[0] = (short)f2bf(f0[0]); w[1] = (short)f2bf(f0[1]);
      w[2] = (short)f2bf(f0[2]); w[3] = (short)f2bf(f0[3]);
      w[4] = (short)f2bf(f1[0]); w[5] = (short)f2bf(f1[1]);
      w[6] = (short)f2bf(f1[2]); w[7] = (short)f2bf(f1[3]);
      wf[kt][nt] = w;
    }
  }

  // gates-phase mapping: thread owns (row gr, cols gj, gj+1) of this wg's
  // 16x32 h-slice; rows are wave-contiguous (wave w -> rows 4w..4w+3).
  const int gr = tid >> 4;
  const int gj = (tid & 15) * 2;
  float c0 = 0.f, c1 = 0.f;

  char*     hb_g = hbuf + (size_t)g * 65536;          // 2 parities x 32KB
  unsigned* flg  = flags + g * 64;

  // ---- P prefetch for s=0 (acc-layout rows r0..r0+3, cols ncol, ncol+16)
  const int r0   = qd * 4;
  const int ncol = wave * 512 + cb * 32 + m16;
  float px0[4], px1[4];
#pragma unroll
  for (int rr = 0; rr < 4; ++rr) {
    int tk  = enc_in[(g * GM + r0 + rr) * Sv + 0];
    px0[rr] = P[(size_t)tk * 2048 + ncol];
    px1[rr] = P[(size_t)tk * 2048 + ncol + 16];
  }

#pragma unroll 1
  for (int s = 0; s < Sv; ++s) {
    const int p = s & 1;

    // ---- stage h (parity p): 8 coherent b128 loads, already fragment-ordered
    // (hi/lo planes split by producer) -> straight b128 LDS writes, no unpack.
    {
      const char* src = hb_g + p * 32768;
      uint4v r8[8];
      const int off0 = tid * 16;
#pragma unroll
      for (int j = 0; j < 8; ++j)
        r8[j] = ld_b128_sys(src + off0 + j * 4096);
      asm volatile("s_waitcnt vmcnt(0)"
                   : "+v"(r8[0]), "+v"(r8[1]), "+v"(r8[2]), "+v"(r8[3]),
                     "+v"(r8[4]), "+v"(r8[5]), "+v"(r8[6]), "+v"(r8[7])
                   :: "memory");
#pragma unroll
      for (int j = 0; j < 8; ++j) {
        int off   = off0 + j * 4096;
        int chunk = off >> 11;
        int rem   = off & 2047;
        int plane = rem >> 10;
        int row   = (rem >> 6) & 15;
        int colo  = rem & 63;
        *(uint4v*)(Asg + chunk * LCH + plane * LPL + row * LRW + colo) = r8[j];
      }
    }
    __syncthreads();   // barrier 1: stage complete

    // ---- MFMA: z_h = (A_hi + A_lo) @ Wh^T
    f32x4 acc0 = {0.f, 0.f, 0.f, 0.f};
    f32x4 acc1 = {0.f, 0.f, 0.f, 0.f};
#pragma unroll
    for (int kt = 0; kt < KT; ++kt) {
      const char* cbase = Asg + kt * LCH + m16 * LRW + qd * 16;
      bf16x8 ah = *(const bf16x8*)(cbase);
      bf16x8 al = *(const bf16x8*)(cbase + LPL);
      acc0 = __builtin_amdgcn_mfma_f32_16x16x32_bf16(ah, wf[kt][0], acc0, 0, 0, 0);
      acc0 = __builtin_amdgcn_mfma_f32_16x16x32_bf16(al, wf[kt][0], acc0, 0, 0, 0);
      acc1 = __builtin_amdgcn_mfma_f32_16x16x32_bf16(ah, wf[kt][1], acc1, 0, 0, 0);
      acc1 = __builtin_amdgcn_mfma_f32_16x16x32_bf16(al, wf[kt][1], acc1, 0, 0, 0);
    }
    // C/D layout: col = lane&15, row = (lane>>4)*4 + reg; add fp32 x-part (P)
#pragma unroll
    for (int rr = 0; rr < 4; ++rr) {
      zbuf[wave][r0 + rr][m16]      = acc0[rr] + px0[rr];
      zbuf[wave][r0 + rr][16 + m16] = acc1[rr] + px1[rr];
    }
    __syncthreads();   // barrier 2: zbuf complete (also: all Asg reads done)

    // ---- gates for (gr, gj), (gr, gj+1)
    float i0 = zbuf[0][gr][gj], i1 = zbuf[0][gr][gj + 1];
    float f0g = zbuf[1][gr][gj], f1g = zbuf[1][gr][gj + 1];
    float g0 = zbuf[2][gr][gj], g1 = zbuf[2][gr][gj + 1];
    float o0 = zbuf[3][gr][gj], o1 = zbuf[3][gr][gj + 1];
    float cn0 = sigm(f0g) * c0 + sigm(i0) * tanh_fast(g0);
    float cn1 = sigm(f1g) * c1 + sigm(i1) * tanh_fast(g1);
    float hn0 = sigm(o0) * tanh_fast(cn0);
    float hn1 = sigm(o1) * tanh_fast(cn1);
    c0 = cn0; c1 = cn1;

    // ---- h store in fragment order: hi pair + lo pair, coherent b32 stores
    {
      unsigned short h0 = f2bf(hn0);
      unsigned short l0 = f2bf(hn0 - bf2f(h0));
      unsigned short h1 = f2bf(hn1);
      unsigned short l1 = f2bf(hn1 - bf2f(h1));
      unsigned hi2 = (unsigned)h0 | ((unsigned)h1 << 16);
      unsigned lo2 = (unsigned)l0 | ((unsigned)l1 << 16);
      char* cbase = hb_g + (p ^ 1) * 32768 + cb * 2048 + gr * 64 + gj * 2;
      __hip_atomic_store((unsigned*)(cbase),        hi2, __ATOMIC_RELAXED, __HIP_MEMORY_SCOPE_AGENT);
      __hip_atomic_store((unsigned*)(cbase + 1024), lo2, __ATOMIC_RELAXED, __HIP_MEMORY_SCOPE_AGENT);
    }
    // enc_out fp16 pair + next-step P gather: issued now so the same vmcnt
    // drain covers them (all in flight concurrently with the h-store acks).
    {
      __half2 h2;
      h2.x = __float2half(hn0);
      h2.y = __float2half(hn1);
      *(__half2*)(enc_out + ((size_t)(g * GM + gr) * Sv + s) * Hv + cb * 32 + gj) = h2;
    }
    {
      int sn = (s + 1 < Sv) ? s + 1 : Sv - 1;
#pragma unroll
      for (int rr = 0; rr < 4; ++rr) {
        int tk  = enc_in[(g * GM + r0 + rr) * Sv + sn];
        px0[rr] = P[(size_t)tk * 2048 + ncol];
        px1[rr] = P[(size_t)tk * 2048 + ncol + 16];
      }
    }

    // ---- per-WAVE completion: drain own stores (per-wave vmcnt), then flag.
    // No intra-wg barrier needed before the flag.
    asm volatile("s_waitcnt vmcnt(0)" ::: "memory");
    if (lane == 0)
      __hip_atomic_store(&flg[cb * 4 + wave], (unsigned)(s + 1),
                         __ATOMIC_RELAXED, __HIP_MEMORY_SCOPE_AGENT);

    // ---- every wave polls all 64 (chunk x wave) flags, one per lane,
    // 2-deep pipelined coherent loads; exit when all lanes >= s+1.
    if (s + 1 < Sv) {
      const unsigned* fp = &flg[lane];
      unsigned tgt = (unsigned)(s + 1);
      unsigned fa = 0, fb = 0;
      asm volatile(
        "global_load_dword %0, %2, off sc0 sc1\n\t"
        "global_load_dword %1, %2, off sc0 sc1\n\t"
        "1:\n\t"
        "s_waitcnt vmcnt(1)\n\t"
        "v_cmp_lt_u32 vcc, %0, %3\n\t"
        "s_cbranch_vccz 2f\n\t"
        "global_load_dword %0, %2, off sc0 sc1\n\t"
        "s_waitcnt vmcnt(1)\n\t"
        "v_cmp_lt_u32 vcc, %1, %3\n\t"
        "s_cbranch_vccz 2f\n\t"
        "global_load_dword %1, %2, off sc0 sc1\n\t"
        "s_branch 1b\n\t"
        "2:\n\t"
        "s_waitcnt vmcnt(0)\n\t"
        : "+v"(fa), "+v"(fb)
        : "v"(fp), "v"(tgt)
        : "vcc", "memory");
    }
    // no post-poll barrier: barrier 1 (post-stage) re-syncs the wg; barrier 2
    // already guaranteed all Asg reads of step s finished before any wave
    // could reach the next stage's writes.
  }
}

// One wg per batch row: scores = enc_out[b] @ We, softmax over S, ctx, then
// pa/pt dots tiled over T. fp32 math, fp16 enc_out reads (16B score loads).
__global__ __launch_bounds__(256)
void attn_out(const __half* __restrict__ enc_out, const float* __restrict__ Wf,
              const float* __restrict__ Wa, const float* __restrict__ ba,
              const float* __restrict__ Wt, const float* __restrict__ bt,
              float* __restrict__ out)
{
  __shared__ float We[512];
  __shared__ float sc[256];
  __shared__ float ctx[512];
  __shared__ float red[8];
  const int tid = threadIdx.x;
  const int b   = blockIdx.x;
  const int wv  = tid >> 6;
  const int ln  = tid & 63;

  We[tid] = Wf[tid];
  We[tid + 256] = Wf[tid + 256];
  __syncthreads();

  // score for s = tid; 16B (half8) loads
  const uint4* r4 = (const uint4*)(enc_out + ((size_t)b * Sv + tid) * Hv);
  float a = 0.f;
#pragma unroll 4
  for (int k = 0; k < 64; ++k) {
    uint4 v = r4[k];
    float2 f0 = __half22float2(__builtin_bit_cast(__half2, v.x));
    float2 f1 = __half22float2(__builtin_bit_cast(__half2, v.y));
    float2 f2 = __half22float2(__builtin_bit_cast(__half2, v.z));
    float2 f3 = __half22float2(__builtin_bit_cast(__half2, v.w));
    const float* w = &We[8 * k];
    a += f0.x * w[0] + f0.y * w[1] + f1.x * w[2] + f1.y * w[3]
       + f2.x * w[4] + f2.y * w[5] + f3.x * w[6] + f3.y * w[7];
  }

  // softmax over S=256
  float m = a;
  for (int off = 32; off; off >>= 1) m = fmaxf(m, __shfl_down(m, off));
  if (ln == 0) red[wv] = m;
  __syncthreads();
  if (tid == 0) red[4] = fmaxf(fmaxf(red[0], red[1]), fmaxf(red[2], red[3]));
  __syncthreads();
  float e = __expf(a - red[4]);
  float ssum = e;
  for (int off = 32; off; off >>= 1) ssum += __shfl_down(ssum, off);
  if (ln == 0) red[wv] = ssum;
  __syncthreads();
  if (tid == 0) red[5] = red[0] + red[1] + red[2] + red[3];
  __syncthreads();
  sc[tid] = e * (1.f / red[5]);
  __syncthreads();

  // ctx[h]: thread owns cols 2*tid, 2*tid+1 (coalesced across threads)
  {
    float a0 = 0.f, a1 = 0.f;
    const __half2* base = (const __half2*)(enc_out + (size_t)b * Sv * Hv) + tid;
#pragma unroll 4
    for (int s2 = 0; s2 < Sv; ++s2) {
      float2 f = __half22float2(base[s2 * (Hv / 2)]);
      float w = sc[s2];
      a0 += w * f.x;
      a1 += w * f.y;
    }
    ctx[2 * tid] = a0;
    ctx[2 * tid + 1] = a1;
  }
  __syncthreads();

  // pa (8) and pt (80) dots; outputs constant over T -> tile
  if (tid < 88) {
    const float* wr = (tid < 8) ? (Wa + tid * Hv) : (Wt + (tid - 8) * Hv);
    float o = (tid < 8) ? ba[tid] : bt[tid - 8];
    for (int k = 0; k < Hv; ++k) o += ctx[k] * wr[k];
    if (tid < 8) {
      float* o0 = out + (size_t)b * Tv * 8;
#pragma unroll
      for (int t = 0; t < Tv; ++t) o0[t * 8 + tid] = o;
    } else {
      int n = tid - 8;
      float* o1 = out + 65536 + (size_t)b * Tv * 80;
#pragma unroll
      for (int t = 0; t < Tv; ++t) o1[t * 80 + n] = o;
    }
  }
}

extern "C" void kernel_launch(void* const* d_in, const int* in_sizes, int n_in,
                              void* d_out, int out_size, void* d_ws, size_t ws_size,
                              hipStream_t stream)
{
  (void)in_sizes; (void)n_in; (void)out_size; (void)ws_size;
  const int*   enc_in = (const int*)d_in[0];
  const float* embed  = (const float*)d_in[2];
  const float* Wi     = (const float*)d_in[3];
  const float* Wh     = (const float*)d_in[4];
  const float* be     = (const float*)d_in[5];
  const float* Wa     = (const float*)d_in[11];
  const float* ba     = (const float*)d_in[12];
  const float* Wt     = (const float*)d_in[13];
  const float* bt     = (const float*)d_in[14];
  const float* Wf     = (const float*)d_in[15];
  // d_in[1] decoder_target, [6..10] decoder weights, [16] bf: dead code

  char* ws = (char*)d_ws;
  unsigned* flags  = (unsigned*)ws;                          // 16 groups x 64 flags = 4KB
  char*     hbuf   = ws + 4096;                              // 16 x 2 x 32KB = 1MB
  float*    P      = (float*)(ws + 4096 + (1u << 20));       // 1000 x 2048 fp32 = 8MB
  __half*   encout = (__half*)(ws + 4096 + (1u << 20) + (8u << 20)); // 64MB

  hipMemsetAsync(d_ws, 0, 4096 + (1u << 20), stream);        // zero flags + h0

  build_P<<<dim3(250), dim3(256), 0, stream>>>(embed, Wi, be, P);
  lstm_enc<<<dim3(256), dim3(256), 0, stream>>>(enc_in, P, Wh, flags, hbuf, encout);
  attn_out<<<dim3(256), dim3(256), 0, stream>>>(encout, Wf, Wa, ba, Wt, bt, (float*)d_out);
}

// Round 6
// 1781.568 us; speedup vs baseline: 1.8775x; 1.8775x over previous
//
#include <hip/hip_runtime.h>
#include <hip/hip_fp16.h>

// B=256,S=256,T=32,H=512,E=128,V=1000,A=8,NT=80.
// Decoder is dead code (softmax shift-invariance over S) -> outputs tiled pa/pt.
// 256 serial LSTM steps: 16 batch-groups x (16 rows, 16 wgs); Wh in registers
// (bf16), h exchanged hi/lo bf16 split (2 MFMAs ~ fp32), x-part precomputed
// (P = embed@Wi.T + b), per-group flag barrier per step.
// R1: threadfence nuked L2 (13us/step). R2/R3: atomic h-loads serialized
// (6.7us). R4: pipelined coherent b128 stage -> 3.1us. R5 REGRESSION: all-wave
// no-sleep poll saturated the coherence fabric + flag stuck behind enc_out/P
// drain -> 12.4us. R6: R4 sync skeleton (wave0 poll + flag right after drain)
// + fused gates via shfl_xor(8) (no zbuf, 2 barriers/step), double-buffered
// Asg, 1-line byte flags, enc_out/P issued under next stage.

#define Sv 256
#define Tv 32
#define Hv 512
#define KT 16          // k-tiles of 32 over K=512
#define GM 16          // batch rows per group
// hbuf per group per parity: [chunk16][plane2(hi,lo)][row16][col32] bf16
//   chunk 2048B, plane 1024B, row 64B. 32KB/parity.
// LDS copy pads rows to 80B: plane 1280B, chunk 2560B.
#define LCH 2560
#define LPL 1280
#define LRW 80

typedef __attribute__((ext_vector_type(8))) short bf16x8;
typedef __attribute__((ext_vector_type(4))) float f32x4;
typedef __attribute__((ext_vector_type(4))) unsigned uint4v;

__device__ __forceinline__ unsigned short f2bf(float x) {   // RNE fp32->bf16
  unsigned u = __builtin_bit_cast(unsigned, x);
  u += 0x7fffu + ((u >> 16) & 1u);
  return (unsigned short)(u >> 16);
}
__device__ __forceinline__ float bf2f(unsigned short h) {
  unsigned u = ((unsigned)h) << 16;
  return __builtin_bit_cast(float, u);
}
__device__ __forceinline__ float sigm(float x) { return 1.0f / (1.0f + __expf(-x)); }
__device__ __forceinline__ float tanh_fast(float x) {
  x = fminf(15.f, fmaxf(-15.f, x));
  float e = __expf(2.f * x);
  return (e - 1.f) / (e + 1.f);
}

// Coherent (device-scope) 16B load: bypasses L1/L2, pipelines like any vmem op.
__device__ __forceinline__ uint4v ld_b128_sys(const void* p) {
  uint4v r;
  asm volatile("global_load_dwordx4 %0, %1, off sc0 sc1" : "=v"(r) : "v"(p));
  return r;
}

// ---- P[v][n] = sum_k embed[v][k]*Wi[n][k] + be[n], fp32. 250 blocks x 4 tokens.
__global__ __launch_bounds__(256)
void build_P(const float* __restrict__ embed, const float* __restrict__ Wi,
             const float* __restrict__ be, float* __restrict__ P)
{
  __shared__ float ev[4][128];
  const int tid = threadIdx.x;
  const int v0  = blockIdx.x * 4;
#pragma unroll
  for (int i = 0; i < 2; ++i) {
    int e = tid + i * 256;
    ev[e >> 7][e & 127] = embed[(v0 + (e >> 7)) * 128 + (e & 127)];
  }
  __syncthreads();
#pragma unroll 1
  for (int cc = 0; cc < 8; ++cc) {
    int n = cc * 256 + tid;
    float b = be[n];
    float a0 = b, a1 = b, a2 = b, a3 = b;
    const f32x4* w = (const f32x4*)(Wi + n * 128);
#pragma unroll
    for (int k4 = 0; k4 < 32; ++k4) {
      f32x4 wv = w[k4];
#pragma unroll
      for (int j = 0; j < 4; ++j) {
        float wj = wv[j];
        int k = k4 * 4 + j;
        a0 += wj * ev[0][k]; a1 += wj * ev[1][k];
        a2 += wj * ev[2][k]; a3 += wj * ev[3][k];
      }
    }
    P[(size_t)(v0 + 0) * 2048 + n] = a0;
    P[(size_t)(v0 + 1) * 2048 + n] = a1;
    P[(size_t)(v0 + 2) * 2048 + n] = a2;
    P[(size_t)(v0 + 3) * 2048 + n] = a3;
  }
}

// flags: per group, 64 BYTE flags (chunk cb x wave w) in ONE 64B line.
__global__ __launch_bounds__(256, 1)
void lstm_enc(const int* __restrict__ enc_in, const float* __restrict__ P,
              const float* __restrict__ Wh,
              unsigned char* __restrict__ flags, char* __restrict__ hbuf,
              __half* __restrict__ enc_out)
{
  __shared__ __attribute__((aligned(16))) char Asg[2][16 * LCH];  // 2x40KB double buffer

  const int tid  = threadIdx.x;
  const int wg   = blockIdx.x;
  const int g    = wg & 15;   // group (members share wg%8 -> same XCD heuristically)
  const int cb   = wg >> 4;   // chunk: owns h-cols [cb*32, cb*32+32)
  const int w    = tid >> 6;  // wave: owns 8 of those cols (w*8..w*8+7), ALL 4 gates
  const int lane = tid & 63;
  const int m16  = lane & 15;
  const int qd   = lane >> 4;
  const bool lowh = (m16 < 8);

  // n-tile0 packs gate0(i) cols (m16<8) and gate1(f) cols (m16>=8);
  // n-tile1 = same + 1024 (gates 2(g), 3(o)).
  const int colw  = w * 8 + (m16 & 7);              // col within the 32-block
  const int ncol0 = (lowh ? 0 : 512) + cb * 32 + colw;
  const int ncol1 = ncol0 + 1024;

  // ---- Wh fragments: lane holds W'[n][k], k = kt*32 + qd*8 + j.
  bf16x8 wf[KT][2];
#pragma unroll
  for (int kt = 0; kt < KT; ++kt) {
#pragma unroll
    for (int nt = 0; nt < 2; ++nt) {
      int n  = (nt == 0) ? ncol0 : ncol1;
      int k0 = kt * 32 + qd * 8;
      const float* src = Wh + (size_t)n * Hv + k0;
      f32x4 f0 = *(const f32x4*)(src);
      f32x4 f1 = *(const f32x4*)(src + 4);
      bf16x8 wv;
      wv[0] = (short)f2bf(f0[0]); wv[1] = (short)f2bf(f0[1]);
      wv[2] = (short)f2bf(f0[2]); wv[3] = (short)f2bf(f0[3]);
      wv[4] = (short)f2bf(f1[0]); wv[5] = (short)f2bf(f1[1]);
      wv[6] = (short)f2bf(f1[2]); wv[7] = (short)f2bf(f1[3]);
      wf[kt][nt] = wv;
    }
  }

  // Lane owns 2 outputs: rows row_a,row_b (=qd*4 + {0,1} or {2,3}), col colw.
  const int row_a = qd * 4 + (lowh ? 0 : 2);
  const int row_b = row_a + 1;
  float cs_a = 0.f, cs_b = 0.f;

  char*          hb_g = hbuf + (size_t)g * 65536;   // 2 parities x 32KB
  unsigned char* flg  = flags + g * 64;

  // P gather rows are the accumulator's 4 rows (qd*4 + rr)
  float px0[4], px1[4];
#pragma unroll
  for (int rr = 0; rr < 4; ++rr) {
    int tk  = enc_in[(g * GM + qd * 4 + rr) * Sv + 0];
    px0[rr] = P[(size_t)tk * 2048 + ncol0];
    px1[rr] = P[(size_t)tk * 2048 + ncol1];
  }

  unsigned short held_a = 0, held_b = 0;   // enc_out fp16 for step s-1

#pragma unroll 1
  for (int s = 0; s < Sv; ++s) {
    const int p = s & 1;

    // ---- phase 1: stage h[s] (8 coherent b128, fragment-ordered) + issue
    // enc_out stores for s-1 + P loads for s+1; ONE vmcnt(0) covers all.
    uint4v r8[8];
    {
      const char* src = hb_g + p * 32768;
      const int off0 = tid * 16;
#pragma unroll
      for (int j = 0; j < 8; ++j)
        r8[j] = ld_b128_sys(src + off0 + j * 4096);
    }
    if (s > 0) {
      int sp = s - 1;
      __half* ea = enc_out + ((size_t)(g * GM + row_a) * Sv + sp) * Hv + cb * 32 + colw;
      __half* eb = enc_out + ((size_t)(g * GM + row_b) * Sv + sp) * Hv + cb * 32 + colw;
      *(unsigned short*)ea = held_a;
      *(unsigned short*)eb = held_b;
    }
    float qx0[4], qx1[4];
    {
      int sn = (s + 1 < Sv) ? s + 1 : Sv - 1;
#pragma unroll
      for (int rr = 0; rr < 4; ++rr) {
        int tk  = enc_in[(g * GM + qd * 4 + rr) * Sv + sn];
        qx0[rr] = P[(size_t)tk * 2048 + ncol0];
        qx1[rr] = P[(size_t)tk * 2048 + ncol1];
      }
    }
    asm volatile("s_waitcnt vmcnt(0)"
                 : "+v"(r8[0]), "+v"(r8[1]), "+v"(r8[2]), "+v"(r8[3]),
                   "+v"(r8[4]), "+v"(r8[5]), "+v"(r8[6]), "+v"(r8[7])
                 :: "memory");
    {
      const int off0 = tid * 16;
#pragma unroll
      for (int j = 0; j < 8; ++j) {
        int off   = off0 + j * 4096;
        int chunk = off >> 11;
        int rem   = off & 2047;
        int plane = rem >> 10;
        int row   = (rem >> 6) & 15;
        int colo  = rem & 63;
        *(uint4v*)(Asg[p] + chunk * LCH + plane * LPL + row * LRW + colo) = r8[j];
      }
    }
    __syncthreads();   // barrier 1: Asg[p] staged

    // ---- MFMA: acc0 = z(i|f cols), acc1 = z(g|o cols)
    f32x4 acc0 = {0.f, 0.f, 0.f, 0.f};
    f32x4 acc1 = {0.f, 0.f, 0.f, 0.f};
#pragma unroll
    for (int kt = 0; kt < KT; ++kt) {
      const char* cbase = Asg[p] + kt * LCH + m16 * LRW + qd * 16;
      bf16x8 ah = *(const bf16x8*)(cbase);
      bf16x8 al = *(const bf16x8*)(cbase + LPL);
      acc0 = __builtin_amdgcn_mfma_f32_16x16x32_bf16(ah, wf[kt][0], acc0, 0, 0, 0);
      acc0 = __builtin_amdgcn_mfma_f32_16x16x32_bf16(al, wf[kt][0], acc0, 0, 0, 0);
      acc1 = __builtin_amdgcn_mfma_f32_16x16x32_bf16(ah, wf[kt][1], acc1, 0, 0, 0);
      acc1 = __builtin_amdgcn_mfma_f32_16x16x32_bf16(al, wf[kt][1], acc1, 0, 0, 0);
    }
    // add fp32 x-part; handoff next step's P
#pragma unroll
    for (int rr = 0; rr < 4; ++rr) {
      acc0[rr] += px0[rr]; acc1[rr] += px1[rr];
      px0[rr] = qx0[rr];   px1[rr] = qx1[rr];
    }

    // ---- fused gates: partner lane (xor 8) holds the other gate pair for the
    // same col; rows qd*4+rr identical across the pair.
    float s0[4], s1[4];
#pragma unroll
    for (int rr = 0; rr < 4; ++rr) {
      s0[rr] = __shfl_xor(acc0[rr], 8);
      s1[rr] = __shfl_xor(acc1[rr], 8);
    }
    float iza = lowh ? acc0[0] : s0[2];
    float izb = lowh ? acc0[1] : s0[3];
    float fza = lowh ? s0[0]   : acc0[2];
    float fzb = lowh ? s0[1]   : acc0[3];
    float gza = lowh ? acc1[0] : s1[2];
    float gzb = lowh ? acc1[1] : s1[3];
    float oza = lowh ? s1[0]   : acc1[2];
    float ozb = lowh ? s1[1]   : acc1[3];

    float cn_a = sigm(fza) * cs_a + sigm(iza) * tanh_fast(gza);
    float cn_b = sigm(fzb) * cs_b + sigm(izb) * tanh_fast(gzb);
    float hn_a = sigm(oza) * tanh_fast(cn_a);
    float hn_b = sigm(ozb) * tanh_fast(cn_b);
    cs_a = cn_a; cs_b = cn_b;

    // ---- h store (fragment order): 4 coherent 2B stores (hi/lo x 2 rows)
    {
      unsigned short ha = f2bf(hn_a), la = f2bf(hn_a - bf2f(ha));
      unsigned short hb = f2bf(hn_b), lb = f2bf(hn_b - bf2f(hb));
      char* dst = hb_g + (p ^ 1) * 32768 + cb * 2048 + colw * 2;
      __hip_atomic_store((unsigned short*)(dst + row_a * 64),        ha, __ATOMIC_RELAXED, __HIP_MEMORY_SCOPE_AGENT);
      __hip_atomic_store((unsigned short*)(dst + row_a * 64 + 1024), la, __ATOMIC_RELAXED, __HIP_MEMORY_SCOPE_AGENT);
      __hip_atomic_store((unsigned short*)(dst + row_b * 64),        hb, __ATOMIC_RELAXED, __HIP_MEMORY_SCOPE_AGENT);
      __hip_atomic_store((unsigned short*)(dst + row_b * 64 + 1024), lb, __ATOMIC_RELAXED, __HIP_MEMORY_SCOPE_AGENT);
      held_a = (unsigned short)__builtin_bit_cast(short, __float2half(hn_a));
      held_b = (unsigned short)__builtin_bit_cast(short, __float2half(hn_b));
    }

    // ---- per-wave drain -> byte flag (NOTHING between drain and flag)
    if (s + 1 < Sv) {
      asm volatile("s_waitcnt vmcnt(0)" ::: "memory");
      if (lane == 0)
        __hip_atomic_store(&flg[cb * 4 + w], (unsigned char)(s + 1),
                           __ATOMIC_RELAXED, __HIP_MEMORY_SCOPE_AGENT);
      // wave0 polls the group's 64 byte-flags (ONE 64B line), 2-deep + sleep
      if (w == 0) {
        const unsigned char* fp = &flg[lane];
        unsigned tgt = (unsigned)(s + 1);
        unsigned fa = 0, fb = 0;
        asm volatile(
          "global_load_ubyte %0, %2, off sc0 sc1\n\t"
          "global_load_ubyte %1, %2, off sc0 sc1\n\t"
          "1:\n\t"
          "s_waitcnt vmcnt(1)\n\t"
          "v_cmp_lt_u32 vcc, %0, %3\n\t"
          "s_cbranch_vccz 2f\n\t"
          "global_load_ubyte %0, %2, off sc0 sc1\n\t"
          "s_sleep 1\n\t"
          "s_waitcnt vmcnt(1)\n\t"
          "v_cmp_lt_u32 vcc, %1, %3\n\t"
          "s_cbranch_vccz 2f\n\t"
          "global_load_ubyte %1, %2, off sc0 sc1\n\t"
          "s_sleep 1\n\t"
          "s_branch 1b\n\t"
          "2:\n\t"
          "s_waitcnt vmcnt(0)\n\t"
          : "+v"(fa), "+v"(fb)
          : "v"(fp), "v"(tgt)
          : "vcc", "memory");
      }
      __syncthreads();   // barrier 2: group step complete (wave0 confirmed)
    }
  }

  // epilogue: enc_out for s=255
  {
    __half* ea = enc_out + ((size_t)(g * GM + row_a) * Sv + (Sv - 1)) * Hv + cb * 32 + colw;
    __half* eb = enc_out + ((size_t)(g * GM + row_b) * Sv + (Sv - 1)) * Hv + cb * 32 + colw;
    *(unsigned short*)ea = held_a;
    *(unsigned short*)eb = held_b;
  }
}

// One wg per batch row: scores = enc_out[b] @ We, softmax over S, ctx, then
// pa/pt dots tiled over T. fp32 math, fp16 enc_out reads (16B score loads).
__global__ __launch_bounds__(256)
void attn_out(const __half* __restrict__ enc_out, const float* __restrict__ Wf,
              const float* __restrict__ Wa, const float* __restrict__ ba,
              const float* __restrict__ Wt, const float* __restrict__ bt,
              float* __restrict__ out)
{
  __shared__ float We[512];
  __shared__ float sc[256];
  __shared__ float ctx[512];
  __shared__ float red[8];
  const int tid = threadIdx.x;
  const int b   = blockIdx.x;
  const int wv  = tid >> 6;
  const int ln  = tid & 63;

  We[tid] = Wf[tid];
  We[tid + 256] = Wf[tid + 256];
  __syncthreads();

  const uint4* r4 = (const uint4*)(enc_out + ((size_t)b * Sv + tid) * Hv);
  float a = 0.f;
#pragma unroll 4
  for (int k = 0; k < 64; ++k) {
    uint4 v = r4[k];
    float2 f0 = __half22float2(__builtin_bit_cast(__half2, v.x));
    float2 f1 = __half22float2(__builtin_bit_cast(__half2, v.y));
    float2 f2 = __half22float2(__builtin_bit_cast(__half2, v.z));
    float2 f3 = __half22float2(__builtin_bit_cast(__half2, v.w));
    const float* wp = &We[8 * k];
    a += f0.x * wp[0] + f0.y * wp[1] + f1.x * wp[2] + f1.y * wp[3]
       + f2.x * wp[4] + f2.y * wp[5] + f3.x * wp[6] + f3.y * wp[7];
  }

  float m = a;
  for (int off = 32; off; off >>= 1) m = fmaxf(m, __shfl_down(m, off));
  if (ln == 0) red[wv] = m;
  __syncthreads();
  if (tid == 0) red[4] = fmaxf(fmaxf(red[0], red[1]), fmaxf(red[2], red[3]));
  __syncthreads();
  float e = __expf(a - red[4]);
  float ssum = e;
  for (int off = 32; off; off >>= 1) ssum += __shfl_down(ssum, off);
  if (ln == 0) red[wv] = ssum;
  __syncthreads();
  if (tid == 0) red[5] = red[0] + red[1] + red[2] + red[3];
  __syncthreads();
  sc[tid] = e * (1.f / red[5]);
  __syncthreads();

  {
    float a0 = 0.f, a1 = 0.f;
    const __half2* base = (const __half2*)(enc_out + (size_t)b * Sv * Hv) + tid;
#pragma unroll 4
    for (int s2 = 0; s2 < Sv; ++s2) {
      float2 f = __half22float2(base[s2 * (Hv / 2)]);
      float w = sc[s2];
      a0 += w * f.x;
      a1 += w * f.y;
    }
    ctx[2 * tid] = a0;
    ctx[2 * tid + 1] = a1;
  }
  __syncthreads();

  if (tid < 88) {
    const float* wr = (tid < 8) ? (Wa + tid * Hv) : (Wt + (tid - 8) * Hv);
    float o = (tid < 8) ? ba[tid] : bt[tid - 8];
    for (int k = 0; k < Hv; ++k) o += ctx[k] * wr[k];
    if (tid < 8) {
      float* o0 = out + (size_t)b * Tv * 8;
#pragma unroll
      for (int t = 0; t < Tv; ++t) o0[t * 8 + tid] = o;
    } else {
      int n = tid - 8;
      float* o1 = out + 65536 + (size_t)b * Tv * 80;
#pragma unroll
      for (int t = 0; t < Tv; ++t) o1[t * 80 + n] = o;
    }
  }
}

extern "C" void kernel_launch(void* const* d_in, const int* in_sizes, int n_in,
                              void* d_out, int out_size, void* d_ws, size_t ws_size,
                              hipStream_t stream)
{
  (void)in_sizes; (void)n_in; (void)out_size; (void)ws_size;
  const int*   enc_in = (const int*)d_in[0];
  const float* embed  = (const float*)d_in[2];
  const float* Wi     = (const float*)d_in[3];
  const float* Wh     = (const float*)d_in[4];
  const float* be     = (const float*)d_in[5];
  const float* Wa     = (const float*)d_in[11];
  const float* ba     = (const float*)d_in[12];
  const float* Wt     = (const float*)d_in[13];
  const float* bt     = (const float*)d_in[14];
  const float* Wf     = (const float*)d_in[15];
  // d_in[1] decoder_target, [6..10] decoder weights, [16] bf: dead code

  char* ws = (char*)d_ws;
  unsigned char* flags = (unsigned char*)ws;                 // 16 groups x 64B = 1KB
  char*     hbuf   = ws + 1024;                              // 16 x 2 x 32KB = 1MB
  float*    P      = (float*)(ws + 1024 + (1u << 20));       // 1000 x 2048 fp32 = 8MB
  __half*   encout = (__half*)(ws + 1024 + (1u << 20) + (8u << 20)); // 64MB

  hipMemsetAsync(d_ws, 0, 1024 + (1u << 20), stream);        // zero flags + h0

  build_P<<<dim3(250), dim3(256), 0, stream>>>(embed, Wi, be, P);
  lstm_enc<<<dim3(256), dim3(256), 0, stream>>>(enc_in, P, Wh, flags, hbuf, encout);
  attn_out<<<dim3(256), dim3(256), 0, stream>>>(encout, Wf, Wa, ba, Wt, bt, (float*)d_out);
}

// Round 8
// 1406.780 us; speedup vs baseline: 2.3776x; 1.2664x over previous
//
#include <hip/hip_runtime.h>
#include <hip/hip_fp16.h>

// B=256,S=256,T=32,H=512,E=128,V=1000,A=8,NT=80.
// Decoder is dead code (softmax shift-invariance over S) -> outputs tiled pa/pt.
// 256 serial LSTM steps: 16 batch-groups x (16 rows, 16 wgs); Wh in registers
// (bf16), h exchanged hi/lo bf16 split (2 MFMAs ~ fp32), x-part precomputed
// (P = embed@Wi.T + b), per-group flag barrier per step.
// R1: threadfence -> buffer_wbl2+inv nuked L2 (13us/step). R2/R3: atomic
// h-loads serialized (6.7us). R4: pipelined coherent b128 stage + wave0 poll
// -> 3.1us (BEST). R5: all-wave no-sleep poll saturated fabric (reverted).
// R6: scattered 2B stores + enc_out on stage path (reverted). R7: seqlock
// retry storm -> livelock/timeout (abandoned).
// R8 (this): R4 skeleton verbatim + the two safe deltas: per-wave drain ->
// per-wave BYTE flag (no pre-flag barrier; 3 barriers/step), and a one-line
// 64-byte flag poll (wave0 only, s_sleep throttled).

#define Sv 256
#define Tv 32
#define Hv 512
#define KT 16          // k-tiles of 32 over K=512 (h only; x-part via P gather)
#define LDSA 520       // padded k-stride (shorts)
#define GM 16          // batch rows per group

typedef __attribute__((ext_vector_type(8))) short bf16x8;
typedef __attribute__((ext_vector_type(4))) float f32x4;
typedef __attribute__((ext_vector_type(4))) unsigned uint4v;

__device__ __forceinline__ unsigned short f2bf(float x) {   // RNE fp32->bf16
  unsigned u = __builtin_bit_cast(unsigned, x);
  u += 0x7fffu + ((u >> 16) & 1u);
  return (unsigned short)(u >> 16);
}
__device__ __forceinline__ float bf2f(unsigned short h) {
  unsigned u = ((unsigned)h) << 16;
  return __builtin_bit_cast(float, u);
}
__device__ __forceinline__ float sigm(float x) { return 1.0f / (1.0f + __expf(-x)); }
__device__ __forceinline__ float tanh_fast(float x) {
  x = fminf(15.f, fmaxf(-15.f, x));
  float e = __expf(2.f * x);
  return (e - 1.f) / (e + 1.f);
}

// Coherent (device-scope) 16B load: bypasses L1/L2, pipelines like any vmem op.
__device__ __forceinline__ uint4v ld_b128_sys(const void* p) {
  uint4v r;
  asm volatile("global_load_dwordx4 %0, %1, off sc0 sc1" : "=v"(r) : "v"(p));
  return r;
}

// ---- P[v][n] = sum_k embed[v][k]*Wi[n][k] + be[n], fp32. 250 blocks x 4 tokens.
__global__ __launch_bounds__(256)
void build_P(const float* __restrict__ embed, const float* __restrict__ Wi,
             const float* __restrict__ be, float* __restrict__ P)
{
  __shared__ float ev[4][128];
  const int tid = threadIdx.x;
  const int v0  = blockIdx.x * 4;
#pragma unroll
  for (int i = 0; i < 2; ++i) {
    int e = tid + i * 256;
    ev[e >> 7][e & 127] = embed[(v0 + (e >> 7)) * 128 + (e & 127)];
  }
  __syncthreads();
#pragma unroll 1
  for (int cc = 0; cc < 8; ++cc) {
    int n = cc * 256 + tid;
    float b = be[n];
    float a0 = b, a1 = b, a2 = b, a3 = b;
    const f32x4* w = (const f32x4*)(Wi + n * 128);
#pragma unroll
    for (int k4 = 0; k4 < 32; ++k4) {
      f32x4 wv = w[k4];
#pragma unroll
      for (int j = 0; j < 4; ++j) {
        float wj = wv[j];
        int k = k4 * 4 + j;
        a0 += wj * ev[0][k]; a1 += wj * ev[1][k];
        a2 += wj * ev[2][k]; a3 += wj * ev[3][k];
      }
    }
    P[(size_t)(v0 + 0) * 2048 + n] = a0;
    P[(size_t)(v0 + 1) * 2048 + n] = a1;
    P[(size_t)(v0 + 2) * 2048 + n] = a2;
    P[(size_t)(v0 + 3) * 2048 + n] = a3;
  }
}

// hbuf: per group g, parity p: [16 rows][512 cols] packed (bf16_hi | bf16_lo<<16).
// flags: per group, 64 BYTE flags (chunk cb x wave) in ONE 64B line.
__global__ __launch_bounds__(256, 1)
void lstm_enc(const int* __restrict__ enc_in, const float* __restrict__ P,
              const float* __restrict__ Wh,
              unsigned char* __restrict__ flags, unsigned* __restrict__ hbuf,
              __half* __restrict__ enc_out)
{
  __shared__ __attribute__((aligned(16))) short Ahi[GM][LDSA];
  __shared__ __attribute__((aligned(16))) short Alo[GM][LDSA];
  __shared__ float zbuf[4][GM][37];

  const int tid  = threadIdx.x;
  const int wg   = blockIdx.x;
  const int g    = wg & 15;   // group (members share wg%8 -> same XCD heuristically; perf only)
  const int cb   = wg >> 4;   // column block: owns z-cols [q*512 + cb*32, +32) per gate q
  const int wave = tid >> 6;  // wave == gate q (0=i,1=f,2=g,3=o)
  const int lane = tid & 63;
  const int m16  = lane & 15;
  const int qd   = lane >> 4;

  // ---- Wh fragments in registers: lane holds W'[n][k] for
  // n = wave*512 + cb*32 + nt*16 + m16, k = kt*32 + qd*8 + j (j=0..7).
  bf16x8 wf[KT][2];
#pragma unroll
  for (int kt = 0; kt < KT; ++kt) {
#pragma unroll
    for (int nt = 0; nt < 2; ++nt) {
      int n  = wave * 512 + cb * 32 + nt * 16 + m16;
      int k0 = kt * 32 + qd * 8;
      const float* src = Wh + (size_t)n * Hv + k0;
      f32x4 f0 = *(const f32x4*)(src);
      f32x4 f1 = *(const f32x4*)(src + 4);
      bf16x8 w;
      w[0] = (short)f2bf(f0[0]); w[1] = (short)f2bf(f0[1]);
      w[2] = (short)f2bf(f0[2]); w[3] = (short)f2bf(f0[3]);
      w[4] = (short)f2bf(f1[0]); w[5] = (short)f2bf(f1[1]);
      w[6] = (short)f2bf(f1[2]); w[7] = (short)f2bf(f1[3]);
      wf[kt][nt] = w;
    }
  }

  // gates-phase mapping: thread owns (row gr, cols gj, gj+1); c-state in regs
  const int gr = tid >> 4;
  const int gj = (tid & 15) * 2;
  float c0 = 0.f, c1 = 0.f;

  unsigned*      hb_g = hbuf + (size_t)g * (2 * GM * Hv);
  unsigned char* flg  = flags + g * 64;

  // ---- P prefetch for s=0 (acc-layout rows r0..r0+3, cols ncol, ncol+16)
  const int r0   = qd * 4;
  const int ncol = wave * 512 + cb * 32 + m16;
  float px0[4], px1[4];
#pragma unroll
  for (int rr = 0; rr < 4; ++rr) {
    int tk  = enc_in[(g * GM + r0 + rr) * Sv + 0];
    px0[rr] = P[(size_t)tk * 2048 + ncol];
    px1[rr] = P[(size_t)tk * 2048 + ncol + 16];
  }

#pragma unroll 1
  for (int s = 0; s < Sv; ++s) {
    const int p = s & 1;

    // ---- stage h (parity p): 8 pipelined coherent b128 loads -> unpack -> LDS
    {
      const unsigned* hsrc = hb_g + (size_t)p * (GM * Hv);
      uint4v r8[8];
#pragma unroll
      for (int j = 0; j < 8; ++j)
        r8[j] = ld_b128_sys((const void*)(hsrc + (j * 256 + tid) * 4));
      asm volatile("s_waitcnt vmcnt(0)"
                   : "+v"(r8[0]), "+v"(r8[1]), "+v"(r8[2]), "+v"(r8[3]),
                     "+v"(r8[4]), "+v"(r8[5]), "+v"(r8[6]), "+v"(r8[7])
                   :: "memory");
      const int col = (4 * tid) & 511;
      const int rb  = tid >> 7;
#pragma unroll
      for (int j = 0; j < 8; ++j) {
        int r = j * 2 + rb;
        unsigned w0 = r8[j][0], w1 = r8[j][1], w2 = r8[j][2], w3 = r8[j][3];
        unsigned hi01 = (w0 & 0xffffu) | (w1 << 16);
        unsigned hi23 = (w2 & 0xffffu) | (w3 << 16);
        unsigned lo01 = (w0 >> 16) | (w1 & 0xffff0000u);
        unsigned lo23 = (w2 >> 16) | (w3 & 0xffff0000u);
        uint2 hv; hv.x = hi01; hv.y = hi23;
        uint2 lv; lv.x = lo01; lv.y = lo23;
        *(uint2*)&Ahi[r][col] = hv;
        *(uint2*)&Alo[r][col] = lv;
      }
    }
    __syncthreads();   // B1: stage complete

    // ---- MFMA: z_h = (A_hi + A_lo) @ Wh^T
    f32x4 acc0 = {0.f, 0.f, 0.f, 0.f};
    f32x4 acc1 = {0.f, 0.f, 0.f, 0.f};
#pragma unroll
    for (int kt = 0; kt < KT; ++kt) {
      bf16x8 ah = *(const bf16x8*)&Ahi[m16][kt * 32 + qd * 8];
      bf16x8 al = *(const bf16x8*)&Alo[m16][kt * 32 + qd * 8];
      acc0 = __builtin_amdgcn_mfma_f32_16x16x32_bf16(ah, wf[kt][0], acc0, 0, 0, 0);
      acc0 = __builtin_amdgcn_mfma_f32_16x16x32_bf16(al, wf[kt][0], acc0, 0, 0, 0);
      acc1 = __builtin_amdgcn_mfma_f32_16x16x32_bf16(ah, wf[kt][1], acc1, 0, 0, 0);
      acc1 = __builtin_amdgcn_mfma_f32_16x16x32_bf16(al, wf[kt][1], acc1, 0, 0, 0);
    }
    // C/D layout: col = lane&15, row = (lane>>4)*4 + reg; add fp32 x-part (P)
#pragma unroll
    for (int rr = 0; rr < 4; ++rr) {
      zbuf[wave][r0 + rr][m16]      = acc0[rr] + px0[rr];
      zbuf[wave][r0 + rr][16 + m16] = acc1[rr] + px1[rr];
    }
    __syncthreads();   // B2: zbuf complete (also fences Ahi reads vs next stage writes)

    // ---- gates for (gr, gj), (gr, gj+1)
    float i0 = zbuf[0][gr][gj], i1 = zbuf[0][gr][gj + 1];
    float f0g = zbuf[1][gr][gj], f1g = zbuf[1][gr][gj + 1];
    float g0 = zbuf[2][gr][gj], g1 = zbuf[2][gr][gj + 1];
    float o0 = zbuf[3][gr][gj], o1 = zbuf[3][gr][gj + 1];
    float cn0 = sigm(f0g) * c0 + sigm(i0) * tanh_fast(g0);
    float cn1 = sigm(f1g) * c1 + sigm(i1) * tanh_fast(g1);
    float hn0 = sigm(o0) * tanh_fast(cn0);
    float hn1 = sigm(o1) * tanh_fast(cn1);
    c0 = cn0; c1 = cn1;

    // ---- h store: one coalesced 8B agent-scope store per thread
    {
      unsigned short h0 = f2bf(hn0);
      unsigned short l0 = f2bf(hn0 - bf2f(h0));
      unsigned short h1 = f2bf(hn1);
      unsigned short l1 = f2bf(hn1 - bf2f(h1));
      unsigned pk0 = (unsigned)h0 | ((unsigned)l0 << 16);
      unsigned pk1 = (unsigned)h1 | ((unsigned)l1 << 16);
      unsigned long long pv = (unsigned long long)pk0 | ((unsigned long long)pk1 << 32);
      __hip_atomic_store(
          (unsigned long long*)(hb_g + (size_t)(p ^ 1) * (GM * Hv) + gr * Hv + cb * 32 + gj),
          pv, __ATOMIC_RELAXED, __HIP_MEMORY_SCOPE_AGENT);
    }

    if (s + 1 < Sv) {
      // ---- per-WAVE drain -> per-wave byte flag (nothing between them)
      asm volatile("s_waitcnt vmcnt(0)" ::: "memory");
      if (lane == 0)
        __hip_atomic_store(&flg[cb * 4 + wave], (unsigned char)(s + 1),
                           __ATOMIC_RELAXED, __HIP_MEMORY_SCOPE_AGENT);
    }

    // enc_out fp16 pair + next-step P gather: issued under the poll window
    {
      __half2 h2;
      h2.x = __float2half(hn0);
      h2.y = __float2half(hn1);
      *(__half2*)(enc_out + ((size_t)(g * GM + gr) * Sv + s) * Hv + cb * 32 + gj) = h2;
    }
    {
      int sn = (s + 1 < Sv) ? s + 1 : Sv - 1;
#pragma unroll
      for (int rr = 0; rr < 4; ++rr) {
        int tk  = enc_in[(g * GM + r0 + rr) * Sv + sn];
        px0[rr] = P[(size_t)tk * 2048 + ncol];
        px1[rr] = P[(size_t)tk * 2048 + ncol + 16];
      }
    }

    if (s + 1 < Sv) {
      // ---- wave0 polls the group's 64 byte-flags (ONE 64B line), throttled
      if (wave == 0) {
        const unsigned char* fp = &flg[lane];
        const unsigned tgt = (unsigned)(s + 1);
        while (true) {
          unsigned f = __hip_atomic_load(fp, __ATOMIC_RELAXED, __HIP_MEMORY_SCOPE_AGENT);
          if (__all((int)(f >= tgt))) break;
          __builtin_amdgcn_s_sleep(1);
        }
      }
      __syncthreads();   // B3: group step confirmed (wave0) -> all waves proceed
    }
  }
}

// One wg per batch row: scores = enc_out[b] @ We, softmax over S, ctx, then
// pa/pt dots tiled over T. fp32 math, fp16 enc_out reads (16B score loads).
__global__ __launch_bounds__(256)
void attn_out(const __half* __restrict__ enc_out, const float* __restrict__ Wf,
              const float* __restrict__ Wa, const float* __restrict__ ba,
              const float* __restrict__ Wt, const float* __restrict__ bt,
              float* __restrict__ out)
{
  __shared__ float We[512];
  __shared__ float sc[256];
  __shared__ float ctx[512];
  __shared__ float red[8];
  const int tid = threadIdx.x;
  const int b   = blockIdx.x;
  const int wv  = tid >> 6;
  const int ln  = tid & 63;

  We[tid] = Wf[tid];
  We[tid + 256] = Wf[tid + 256];
  __syncthreads();

  const uint4* r4 = (const uint4*)(enc_out + ((size_t)b * Sv + tid) * Hv);
  float a = 0.f;
#pragma unroll 4
  for (int k = 0; k < 64; ++k) {
    uint4 v = r4[k];
    float2 f0 = __half22float2(__builtin_bit_cast(__half2, v.x));
    float2 f1 = __half22float2(__builtin_bit_cast(__half2, v.y));
    float2 f2 = __half22float2(__builtin_bit_cast(__half2, v.z));
    float2 f3 = __half22float2(__builtin_bit_cast(__half2, v.w));
    const float* wp = &We[8 * k];
    a += f0.x * wp[0] + f0.y * wp[1] + f1.x * wp[2] + f1.y * wp[3]
       + f2.x * wp[4] + f2.y * wp[5] + f3.x * wp[6] + f3.y * wp[7];
  }

  float m = a;
  for (int off = 32; off; off >>= 1) m = fmaxf(m, __shfl_down(m, off));
  if (ln == 0) red[wv] = m;
  __syncthreads();
  if (tid == 0) red[4] = fmaxf(fmaxf(red[0], red[1]), fmaxf(red[2], red[3]));
  __syncthreads();
  float e = __expf(a - red[4]);
  float ssum = e;
  for (int off = 32; off; off >>= 1) ssum += __shfl_down(ssum, off);
  if (ln == 0) red[wv] = ssum;
  __syncthreads();
  if (tid == 0) red[5] = red[0] + red[1] + red[2] + red[3];
  __syncthreads();
  sc[tid] = e * (1.f / red[5]);
  __syncthreads();

  {
    float a0 = 0.f, a1 = 0.f;
    const __half2* base = (const __half2*)(enc_out + (size_t)b * Sv * Hv) + tid;
#pragma unroll 4
    for (int s2 = 0; s2 < Sv; ++s2) {
      float2 f = __half22float2(base[s2 * (Hv / 2)]);
      float w = sc[s2];
      a0 += w * f.x;
      a1 += w * f.y;
    }
    ctx[2 * tid] = a0;
    ctx[2 * tid + 1] = a1;
  }
  __syncthreads();

  if (tid < 88) {
    const float* wr = (tid < 8) ? (Wa + tid * Hv) : (Wt + (tid - 8) * Hv);
    float o = (tid < 8) ? ba[tid] : bt[tid - 8];
    for (int k = 0; k < Hv; ++k) o += ctx[k] * wr[k];
    if (tid < 8) {
      float* o0 = out + (size_t)b * Tv * 8;
#pragma unroll
      for (int t = 0; t < Tv; ++t) o0[t * 8 + tid] = o;
    } else {
      int n = tid - 8;
      float* o1 = out + 65536 + (size_t)b * Tv * 80;
#pragma unroll
      for (int t = 0; t < Tv; ++t) o1[t * 80 + n] = o;
    }
  }
}

extern "C" void kernel_launch(void* const* d_in, const int* in_sizes, int n_in,
                              void* d_out, int out_size, void* d_ws, size_t ws_size,
                              hipStream_t stream)
{
  (void)in_sizes; (void)n_in; (void)out_size; (void)ws_size;
  const int*   enc_in = (const int*)d_in[0];
  const float* embed  = (const float*)d_in[2];
  const float* Wi     = (const float*)d_in[3];
  const float* Wh     = (const float*)d_in[4];
  const float* be     = (const float*)d_in[5];
  const float* Wa     = (const float*)d_in[11];
  const float* ba     = (const float*)d_in[12];
  const float* Wt     = (const float*)d_in[13];
  const float* bt     = (const float*)d_in[14];
  const float* Wf     = (const float*)d_in[15];
  // d_in[1] decoder_target, [6..10] decoder weights, [16] bf: dead code

  char* ws = (char*)d_ws;
  unsigned char* flags = (unsigned char*)ws;                 // 16 groups x 64B = 1KB (4KB reserved)
  unsigned* hbuf   = (unsigned*)(ws + 4096);                 // 16 x 2 x 16x512 packed = 1MB
  float*    P      = (float*)(ws + 4096 + (1u << 20));       // 1000 x 2048 fp32 = 8MB
  __half*   encout = (__half*)(ws + 4096 + (1u << 20) + (8u << 20)); // 64MB

  hipMemsetAsync(d_ws, 0, 4096 + (1u << 20), stream);        // zero flags + h0

  build_P<<<dim3(250), dim3(256), 0, stream>>>(embed, Wi, be, P);
  lstm_enc<<<dim3(256), dim3(256), 0, stream>>>(enc_in, P, Wh, flags, hbuf, encout);
  attn_out<<<dim3(256), dim3(256), 0, stream>>>(encout, Wf, Wa, ba, Wt, bt, (float*)d_out);
}

// Round 10
// 1294.038 us; speedup vs baseline: 2.5848x; 1.0871x over previous
//
#include <hip/hip_runtime.h>
#include <hip/hip_fp16.h>

// B=256,S=256,T=32,H=512,E=128,V=1000,A=8,NT=80.
// Decoder is dead code (softmax shift-invariance over S) -> outputs tiled pa/pt.
// 256 serial LSTM steps; 16 independent batch-groups of 16 rows.
// History: R1 threadfence nuked L2 (13us/step). R2/R3 atomic h-loads
// serialized (6.7). R4 pipelined sc0sc1 b128 stage + wg barrier + tid0 dword
// flag + wave0 2-deep poll -> 3.1us/step, 793us (BEST). R5 poll storm. R6
// scattered 2B stores. R7 seqlock retry livelock. R8 byte flags/slow poll.
// R9 sc0-only "L2-local" exchange -> NOT coherent -> hang.
// Verdict: R4's protocol is frozen. R10 (this): GROUP PAIRING. 128 wgs; each
// wg runs TWO independent groups (gA=wg&7, gB=gA+8) with shared Wh registers,
// interleaved A-half/B-half per iteration, and ONE R4 sync transaction
// (drain+flag+poll+barrier) per iteration = per TWO group-steps. The B-half
// compute fills A's former wait windows. Primitives byte-identical to R4.

#define Sv 256
#define Tv 32
#define Hv 512
#define KT 16          // k-tiles of 32 over K=512 (h only; x-part via P gather)
#define LDSA 520       // padded k-stride (shorts)
#define GM 16          // batch rows per group

typedef __attribute__((ext_vector_type(8))) short bf16x8;
typedef __attribute__((ext_vector_type(4))) float f32x4;
typedef __attribute__((ext_vector_type(4))) unsigned uint4v;

__device__ __forceinline__ unsigned short f2bf(float x) {   // RNE fp32->bf16
  unsigned u = __builtin_bit_cast(unsigned, x);
  u += 0x7fffu + ((u >> 16) & 1u);
  return (unsigned short)(u >> 16);
}
__device__ __forceinline__ float bf2f(unsigned short h) {
  unsigned u = ((unsigned)h) << 16;
  return __builtin_bit_cast(float, u);
}
__device__ __forceinline__ float sigm(float x) { return 1.0f / (1.0f + __expf(-x)); }
__device__ __forceinline__ float tanh_fast(float x) {
  x = fminf(15.f, fmaxf(-15.f, x));
  float e = __expf(2.f * x);
  return (e - 1.f) / (e + 1.f);
}

// Coherent (device-scope) 16B load: bypasses L1/L2, pipelines like any vmem op.
__device__ __forceinline__ uint4v ld_b128_sys(const void* p) {
  uint4v r;
  asm volatile("global_load_dwordx4 %0, %1, off sc0 sc1" : "=v"(r) : "v"(p));
  return r;
}

// ---- P[v][n] = sum_k embed[v][k]*Wi[n][k] + be[n], fp32. 250 blocks x 4 tokens.
__global__ __launch_bounds__(256)
void build_P(const float* __restrict__ embed, const float* __restrict__ Wi,
             const float* __restrict__ be, float* __restrict__ P)
{
  __shared__ float ev[4][128];
  const int tid = threadIdx.x;
  const int v0  = blockIdx.x * 4;
#pragma unroll
  for (int i = 0; i < 2; ++i) {
    int e = tid + i * 256;
    ev[e >> 7][e & 127] = embed[(v0 + (e >> 7)) * 128 + (e & 127)];
  }
  __syncthreads();
#pragma unroll 1
  for (int cc = 0; cc < 8; ++cc) {
    int n = cc * 256 + tid;
    float b = be[n];
    float a0 = b, a1 = b, a2 = b, a3 = b;
    const f32x4* w = (const f32x4*)(Wi + n * 128);
#pragma unroll
    for (int k4 = 0; k4 < 32; ++k4) {
      f32x4 wv = w[k4];
#pragma unroll
      for (int j = 0; j < 4; ++j) {
        float wj = wv[j];
        int k = k4 * 4 + j;
        a0 += wj * ev[0][k]; a1 += wj * ev[1][k];
        a2 += wj * ev[2][k]; a3 += wj * ev[3][k];
      }
    }
    P[(size_t)(v0 + 0) * 2048 + n] = a0;
    P[(size_t)(v0 + 1) * 2048 + n] = a1;
    P[(size_t)(v0 + 2) * 2048 + n] = a2;
    P[(size_t)(v0 + 3) * 2048 + n] = a3;
  }
}

// hbuf: per group g, parity p: [16 rows][512 cols] packed (bf16_hi|bf16_lo<<16).
// flags: per PAIR gl, 16 dword flags (one 64B line); flag s+1 = this wg
// finished BOTH groups' step s and all its h stores are acked (device scope).
__global__ __launch_bounds__(256, 1)
void lstm_enc(const int* __restrict__ enc_in, const float* __restrict__ P,
              const float* __restrict__ Wh,
              unsigned* __restrict__ flags, unsigned* __restrict__ hbuf,
              __half* __restrict__ enc_out)
{
  __shared__ __attribute__((aligned(16))) short AhiA[GM][LDSA];
  __shared__ __attribute__((aligned(16))) short AloA[GM][LDSA];
  __shared__ __attribute__((aligned(16))) short AhiB[GM][LDSA];
  __shared__ __attribute__((aligned(16))) short AloB[GM][LDSA];
  __shared__ float zbuf[4][GM][37];

  const int tid  = threadIdx.x;
  const int wg   = blockIdx.x;
  const int gl   = wg & 7;    // pair id; members share wg%8 -> same XCD heuristically (perf only)
  const int cb   = wg >> 3;   // column block 0..15: owns z-cols [q*512+cb*32, +32) per gate q
  const int gA   = gl;
  const int gB   = gl + 8;
  const int wave = tid >> 6;  // wave == gate q
  const int lane = tid & 63;
  const int m16  = lane & 15;
  const int qd   = lane >> 4;

  // ---- Wh fragments in registers (SHARED by both groups): lane holds W'[n][k]
  // for n = wave*512 + cb*32 + nt*16 + m16, k = kt*32 + qd*8 + j.
  bf16x8 wf[KT][2];
#pragma unroll
  for (int kt = 0; kt < KT; ++kt) {
#pragma unroll
    for (int nt = 0; nt < 2; ++nt) {
      int n  = wave * 512 + cb * 32 + nt * 16 + m16;
      int k0 = kt * 32 + qd * 8;
      const float* src = Wh + (size_t)n * Hv + k0;
      f32x4 f0 = *(const f32x4*)(src);
      f32x4 f1 = *(const f32x4*)(src + 4);
      bf16x8 w;
      w[0] = (short)f2bf(f0[0]); w[1] = (short)f2bf(f0[1]);
      w[2] = (short)f2bf(f0[2]); w[3] = (short)f2bf(f0[3]);
      w[4] = (short)f2bf(f1[0]); w[5] = (short)f2bf(f1[1]);
      w[6] = (short)f2bf(f1[2]); w[7] = (short)f2bf(f1[3]);
      wf[kt][nt] = w;
    }
  }

  const int gr = tid >> 4;          // gates row (group-local)
  const int gj = (tid & 15) * 2;    // gates col pair
  float cA0 = 0.f, cA1 = 0.f, cB0 = 0.f, cB1 = 0.f;

  unsigned* hbA = hbuf + (size_t)gA * (2 * GM * Hv);
  unsigned* hbB = hbuf + (size_t)gB * (2 * GM * Hv);
  unsigned* flg = flags + gl * 16;

  // ---- P prefetch for s=0 (acc rows r0..r0+3, cols ncol, ncol+16), both groups
  const int r0   = qd * 4;
  const int ncol = wave * 512 + cb * 32 + m16;
  float pxA0[4], pxA1[4], pxB0[4], pxB1[4];
#pragma unroll
  for (int rr = 0; rr < 4; ++rr) {
    int ta = enc_in[(gA * GM + r0 + rr) * Sv + 0];
    int tb = enc_in[(gB * GM + r0 + rr) * Sv + 0];
    pxA0[rr] = P[(size_t)ta * 2048 + ncol];
    pxA1[rr] = P[(size_t)ta * 2048 + ncol + 16];
    pxB0[rr] = P[(size_t)tb * 2048 + ncol];
    pxB1[rr] = P[(size_t)tb * 2048 + ncol + 16];
  }

#pragma unroll 1
  for (int s = 0; s < Sv; ++s) {
    const int p = s & 1;

    // ---- co-issue stage loads for BOTH groups (A first, then B; volatile asm
    // preserves issue order; vmcnt retires in order).
    uint4v ra8[8], rb8[8];
    {
      const unsigned* sa = hbA + (size_t)p * (GM * Hv);
      const unsigned* sb = hbB + (size_t)p * (GM * Hv);
#pragma unroll
      for (int j = 0; j < 8; ++j)
        ra8[j] = ld_b128_sys((const void*)(sa + (j * 256 + tid) * 4));
#pragma unroll
      for (int j = 0; j < 8; ++j)
        rb8[j] = ld_b128_sys((const void*)(sb + (j * 256 + tid) * 4));
    }
    // wait for A's 8 (leaves B's 8 outstanding)
    asm volatile("s_waitcnt vmcnt(8)"
                 : "+v"(ra8[0]), "+v"(ra8[1]), "+v"(ra8[2]), "+v"(ra8[3]),
                   "+v"(ra8[4]), "+v"(ra8[5]), "+v"(ra8[6]), "+v"(ra8[7])
                 :: "memory");
    const int col = (4 * tid) & 511;
    const int rbk = tid >> 7;
#pragma unroll
    for (int j = 0; j < 8; ++j) {
      int r = j * 2 + rbk;
      unsigned w0 = ra8[j][0], w1 = ra8[j][1], w2 = ra8[j][2], w3 = ra8[j][3];
      uint2 hv, lv;
      hv.x = (w0 & 0xffffu) | (w1 << 16);
      hv.y = (w2 & 0xffffu) | (w3 << 16);
      lv.x = (w0 >> 16) | (w1 & 0xffff0000u);
      lv.y = (w2 >> 16) | (w3 & 0xffff0000u);
      *(uint2*)&AhiA[r][col] = hv;
      *(uint2*)&AloA[r][col] = lv;
    }
    __syncthreads();   // B1: A staged

    // ---- MFMA A
    f32x4 acc0 = {0.f, 0.f, 0.f, 0.f};
    f32x4 acc1 = {0.f, 0.f, 0.f, 0.f};
#pragma unroll
    for (int kt = 0; kt < KT; ++kt) {
      bf16x8 ah = *(const bf16x8*)&AhiA[m16][kt * 32 + qd * 8];
      bf16x8 al = *(const bf16x8*)&AloA[m16][kt * 32 + qd * 8];
      acc0 = __builtin_amdgcn_mfma_f32_16x16x32_bf16(ah, wf[kt][0], acc0, 0, 0, 0);
      acc0 = __builtin_amdgcn_mfma_f32_16x16x32_bf16(al, wf[kt][0], acc0, 0, 0, 0);
      acc1 = __builtin_amdgcn_mfma_f32_16x16x32_bf16(ah, wf[kt][1], acc1, 0, 0, 0);
      acc1 = __builtin_amdgcn_mfma_f32_16x16x32_bf16(al, wf[kt][1], acc1, 0, 0, 0);
    }
#pragma unroll
    for (int rr = 0; rr < 4; ++rr) {
      zbuf[wave][r0 + rr][m16]      = acc0[rr] + pxA0[rr];
      zbuf[wave][r0 + rr][16 + m16] = acc1[rr] + pxA1[rr];
    }
    __syncthreads();   // B2: zbuf(A) complete

    // ---- gates A
    float hnA0, hnA1;
    {
      float i0 = zbuf[0][gr][gj], i1 = zbuf[0][gr][gj + 1];
      float f0g = zbuf[1][gr][gj], f1g = zbuf[1][gr][gj + 1];
      float g0 = zbuf[2][gr][gj], g1 = zbuf[2][gr][gj + 1];
      float o0 = zbuf[3][gr][gj], o1 = zbuf[3][gr][gj + 1];
      float cn0 = sigm(f0g) * cA0 + sigm(i0) * tanh_fast(g0);
      float cn1 = sigm(f1g) * cA1 + sigm(i1) * tanh_fast(g1);
      hnA0 = sigm(o0) * tanh_fast(cn0);
      hnA1 = sigm(o1) * tanh_fast(cn1);
      cA0 = cn0; cA1 = cn1;
    }
    // h_A store: one coalesced 8B agent-scope store (ack drains at B3)
    {
      unsigned short h0 = f2bf(hnA0), l0 = f2bf(hnA0 - bf2f(h0));
      unsigned short h1 = f2bf(hnA1), l1 = f2bf(hnA1 - bf2f(h1));
      unsigned long long pv = (unsigned long long)((unsigned)h0 | ((unsigned)l0 << 16))
                            | ((unsigned long long)((unsigned)h1 | ((unsigned)l1 << 16)) << 32);
      __hip_atomic_store(
          (unsigned long long*)(hbA + (size_t)(p ^ 1) * (GM * Hv) + gr * Hv + cb * 32 + gj),
          pv, __ATOMIC_RELAXED, __HIP_MEMORY_SCOPE_AGENT);
    }

    // ---- B data arrived during MFMA A: allow 1 outstanding (the h_A store)
    asm volatile("s_waitcnt vmcnt(1)"
                 : "+v"(rb8[0]), "+v"(rb8[1]), "+v"(rb8[2]), "+v"(rb8[3]),
                   "+v"(rb8[4]), "+v"(rb8[5]), "+v"(rb8[6]), "+v"(rb8[7])
                 :: "memory");
#pragma unroll
    for (int j = 0; j < 8; ++j) {
      int r = j * 2 + rbk;
      unsigned w0 = rb8[j][0], w1 = rb8[j][1], w2 = rb8[j][2], w3 = rb8[j][3];
      uint2 hv, lv;
      hv.x = (w0 & 0xffffu) | (w1 << 16);
      hv.y = (w2 & 0xffffu) | (w3 << 16);
      lv.x = (w0 >> 16) | (w1 & 0xffff0000u);
      lv.y = (w2 >> 16) | (w3 & 0xffff0000u);
      *(uint2*)&AhiB[r][col] = hv;
      *(uint2*)&AloB[r][col] = lv;
    }
    __syncthreads();   // B1': B staged (also: all gates-A zbuf reads done)

    // ---- MFMA B
    acc0 = (f32x4){0.f, 0.f, 0.f, 0.f};
    acc1 = (f32x4){0.f, 0.f, 0.f, 0.f};
#pragma unroll
    for (int kt = 0; kt < KT; ++kt) {
      bf16x8 ah = *(const bf16x8*)&AhiB[m16][kt * 32 + qd * 8];
      bf16x8 al = *(const bf16x8*)&AloB[m16][kt * 32 + qd * 8];
      acc0 = __builtin_amdgcn_mfma_f32_16x16x32_bf16(ah, wf[kt][0], acc0, 0, 0, 0);
      acc0 = __builtin_amdgcn_mfma_f32_16x16x32_bf16(al, wf[kt][0], acc0, 0, 0, 0);
      acc1 = __builtin_amdgcn_mfma_f32_16x16x32_bf16(ah, wf[kt][1], acc1, 0, 0, 0);
      acc1 = __builtin_amdgcn_mfma_f32_16x16x32_bf16(al, wf[kt][1], acc1, 0, 0, 0);
    }
#pragma unroll
    for (int rr = 0; rr < 4; ++rr) {
      zbuf[wave][r0 + rr][m16]      = acc0[rr] + pxB0[rr];
      zbuf[wave][r0 + rr][16 + m16] = acc1[rr] + pxB1[rr];
    }
    __syncthreads();   // B2': zbuf(B) complete

    // ---- gates B
    float hnB0, hnB1;
    {
      float i0 = zbuf[0][gr][gj], i1 = zbuf[0][gr][gj + 1];
      float f0g = zbuf[1][gr][gj], f1g = zbuf[1][gr][gj + 1];
      float g0 = zbuf[2][gr][gj], g1 = zbuf[2][gr][gj + 1];
      float o0 = zbuf[3][gr][gj], o1 = zbuf[3][gr][gj + 1];
      float cn0 = sigm(f0g) * cB0 + sigm(i0) * tanh_fast(g0);
      float cn1 = sigm(f1g) * cB1 + sigm(i1) * tanh_fast(g1);
      hnB0 = sigm(o0) * tanh_fast(cn0);
      hnB1 = sigm(o1) * tanh_fast(cn1);
      cB0 = cn0; cB1 = cn1;
    }
    {
      unsigned short h0 = f2bf(hnB0), l0 = f2bf(hnB0 - bf2f(h0));
      unsigned short h1 = f2bf(hnB1), l1 = f2bf(hnB1 - bf2f(h1));
      unsigned long long pv = (unsigned long long)((unsigned)h0 | ((unsigned)l0 << 16))
                            | ((unsigned long long)((unsigned)h1 | ((unsigned)l1 << 16)) << 32);
      __hip_atomic_store(
          (unsigned long long*)(hbB + (size_t)(p ^ 1) * (GM * Hv) + gr * Hv + cb * 32 + gj),
          pv, __ATOMIC_RELAXED, __HIP_MEMORY_SCOPE_AGENT);
    }

    if (s + 1 < Sv) {
      // ---- ONE R4 sync transaction for the pair:
      // B3 drains ALL stores (h_A long in flight, h_B fresh), then one flag.
      __syncthreads();
      if (tid == 0)
        __hip_atomic_store(&flg[cb], (unsigned)(s + 1),
                           __ATOMIC_RELAXED, __HIP_MEMORY_SCOPE_AGENT);

      // enc_out (both groups, step s) + P gathers (both groups, step s+1):
      // issued under the poll window, drained implicitly later.
      {
        __half2 ha; ha.x = __float2half(hnA0); ha.y = __float2half(hnA1);
        __half2 hb; hb.x = __float2half(hnB0); hb.y = __float2half(hnB1);
        *(__half2*)(enc_out + ((size_t)(gA * GM + gr) * Sv + s) * Hv + cb * 32 + gj) = ha;
        *(__half2*)(enc_out + ((size_t)(gB * GM + gr) * Sv + s) * Hv + cb * 32 + gj) = hb;
      }
      {
        int sn = s + 1;
#pragma unroll
        for (int rr = 0; rr < 4; ++rr) {
          int ta = enc_in[(gA * GM + r0 + rr) * Sv + sn];
          int tb = enc_in[(gB * GM + r0 + rr) * Sv + sn];
          pxA0[rr] = P[(size_t)ta * 2048 + ncol];
          pxA1[rr] = P[(size_t)ta * 2048 + ncol + 16];
          pxB0[rr] = P[(size_t)tb * 2048 + ncol];
          pxB1[rr] = P[(size_t)tb * 2048 + ncol + 16];
        }
      }

      // ---- wave0 2-deep pipelined poll of the pair's 16 dword flags (R4 asm)
      if (wave == 0) {
        const unsigned* fp = &flg[lane & 15];
        unsigned tgt = (unsigned)(s + 1);
        unsigned fa = 0, fb = 0;
        asm volatile(
          "global_load_dword %0, %2, off sc0 sc1\n\t"
          "global_load_dword %1, %2, off sc0 sc1\n\t"
          "1:\n\t"
          "s_waitcnt vmcnt(1)\n\t"
          "v_cmp_lt_u32 vcc, %0, %3\n\t"
          "s_cbranch_vccz 2f\n\t"
          "global_load_dword %0, %2, off sc0 sc1\n\t"
          "s_waitcnt vmcnt(1)\n\t"
          "v_cmp_lt_u32 vcc, %1, %3\n\t"
          "s_cbranch_vccz 2f\n\t"
          "global_load_dword %1, %2, off sc0 sc1\n\t"
          "s_branch 1b\n\t"
          "2:\n\t"
          "s_waitcnt vmcnt(0)\n\t"
          : "+v"(fa), "+v"(fb)
          : "v"(fp), "v"(tgt)
          : "vcc", "memory");
      }
      __syncthreads();   // B4: pair step confirmed
    } else {
      // last step: just write enc_out for both groups
      __half2 ha; ha.x = __float2half(hnA0); ha.y = __float2half(hnA1);
      __half2 hb; hb.x = __float2half(hnB0); hb.y = __float2half(hnB1);
      *(__half2*)(enc_out + ((size_t)(gA * GM + gr) * Sv + s) * Hv + cb * 32 + gj) = ha;
      *(__half2*)(enc_out + ((size_t)(gB * GM + gr) * Sv + s) * Hv + cb * 32 + gj) = hb;
    }
  }
}

// One wg per batch row: scores = enc_out[b] @ We, softmax over S, ctx, then
// pa/pt dots tiled over T. fp32 math, fp16 enc_out reads (16B score loads).
__global__ __launch_bounds__(256)
void attn_out(const __half* __restrict__ enc_out, const float* __restrict__ Wf,
              const float* __restrict__ Wa, const float* __restrict__ ba,
              const float* __restrict__ Wt, const float* __restrict__ bt,
              float* __restrict__ out)
{
  __shared__ float We[512];
  __shared__ float sc[256];
  __shared__ float ctx[512];
  __shared__ float red[8];
  const int tid = threadIdx.x;
  const int b   = blockIdx.x;
  const int wv  = tid >> 6;
  const int ln  = tid & 63;

  We[tid] = Wf[tid];
  We[tid + 256] = Wf[tid + 256];
  __syncthreads();

  const uint4* r4 = (const uint4*)(enc_out + ((size_t)b * Sv + tid) * Hv);
  float a = 0.f;
#pragma unroll 4
  for (int k = 0; k < 64; ++k) {
    uint4 v = r4[k];
    float2 f0 = __half22float2(__builtin_bit_cast(__half2, v.x));
    float2 f1 = __half22float2(__builtin_bit_cast(__half2, v.y));
    float2 f2 = __half22float2(__builtin_bit_cast(__half2, v.z));
    float2 f3 = __half22float2(__builtin_bit_cast(__half2, v.w));
    const float* wp = &We[8 * k];
    a += f0.x * wp[0] + f0.y * wp[1] + f1.x * wp[2] + f1.y * wp[3]
       + f2.x * wp[4] + f2.y * wp[5] + f3.x * wp[6] + f3.y * wp[7];
  }

  float m = a;
  for (int off = 32; off; off >>= 1) m = fmaxf(m, __shfl_down(m, off));
  if (ln == 0) red[wv] = m;
  __syncthreads();
  if (tid == 0) red[4] = fmaxf(fmaxf(red[0], red[1]), fmaxf(red[2], red[3]));
  __syncthreads();
  float e = __expf(a - red[4]);
  float ssum = e;
  for (int off = 32; off; off >>= 1) ssum += __shfl_down(ssum, off);
  if (ln == 0) red[wv] = ssum;
  __syncthreads();
  if (tid == 0) red[5] = red[0] + red[1] + red[2] + red[3];
  __syncthreads();
  sc[tid] = e * (1.f / red[5]);
  __syncthreads();

  {
    float a0 = 0.f, a1 = 0.f;
    const __half2* base = (const __half2*)(enc_out + (size_t)b * Sv * Hv) + tid;
#pragma unroll 4
    for (int s2 = 0; s2 < Sv; ++s2) {
      float2 f = __half22float2(base[s2 * (Hv / 2)]);
      float w = sc[s2];
      a0 += w * f.x;
      a1 += w * f.y;
    }
    ctx[2 * tid] = a0;
    ctx[2 * tid + 1] = a1;
  }
  __syncthreads();

  if (tid < 88) {
    const float* wr = (tid < 8) ? (Wa + tid * Hv) : (Wt + (tid - 8) * Hv);
    float o = (tid < 8) ? ba[tid] : bt[tid - 8];
    for (int k = 0; k < Hv; ++k) o += ctx[k] * wr[k];
    if (tid < 8) {
      float* o0 = out + (size_t)b * Tv * 8;
#pragma unroll
      for (int t = 0; t < Tv; ++t) o0[t * 8 + tid] = o;
    } else {
      int n = tid - 8;
      float* o1 = out + 65536 + (size_t)b * Tv * 80;
#pragma unroll
      for (int t = 0; t < Tv; ++t) o1[t * 80 + n] = o;
    }
  }
}

extern "C" void kernel_launch(void* const* d_in, const int* in_sizes, int n_in,
                              void* d_out, int out_size, void* d_ws, size_t ws_size,
                              hipStream_t stream)
{
  (void)in_sizes; (void)n_in; (void)out_size; (void)ws_size;
  const int*   enc_in = (const int*)d_in[0];
  const float* embed  = (const float*)d_in[2];
  const float* Wi     = (const float*)d_in[3];
  const float* Wh     = (const float*)d_in[4];
  const float* be     = (const float*)d_in[5];
  const float* Wa     = (const float*)d_in[11];
  const float* ba     = (const float*)d_in[12];
  const float* Wt     = (const float*)d_in[13];
  const float* bt     = (const float*)d_in[14];
  const float* Wf     = (const float*)d_in[15];
  // d_in[1] decoder_target, [6..10] decoder weights, [16] bf: dead code

  char* ws = (char*)d_ws;
  unsigned* flags  = (unsigned*)ws;                          // 8 pairs x 64B = 512B (4KB reserved)
  unsigned* hbuf   = (unsigned*)(ws + 4096);                 // 16 x 2 x 16x512 packed = 1MB
  float*    P      = (float*)(ws + 4096 + (1u << 20));       // 1000 x 2048 fp32 = 8MB
  __half*   encout = (__half*)(ws + 4096 + (1u << 20) + (8u << 20)); // 64MB

  hipMemsetAsync(d_ws, 0, 4096 + (1u << 20), stream);        // zero flags + h0

  build_P<<<dim3(250), dim3(256), 0, stream>>>(embed, Wi, be, P);
  lstm_enc<<<dim3(128), dim3(256), 0, stream>>>(enc_in, P, Wh, flags, hbuf, encout);
  attn_out<<<dim3(256), dim3(256), 0, stream>>>(encout, Wf, Wa, ba, Wt, bt, (float*)d_out);
}

// Round 11
// 808.947 us; speedup vs baseline: 4.1348x; 1.5997x over previous
//
#include <hip/hip_runtime.h>
#include <hip/hip_fp16.h>

// B=256,S=256,T=32,H=512,E=128,V=1000,A=8,NT=80.
// Decoder is dead code (softmax shift-invariance over S) -> outputs tiled pa/pt.
// 256 serial LSTM steps: 16 batch-groups x (16 rows, 16 wgs); Wh in registers,
// x-part precomputed (P = embed@Wi.T + b, fp32 gather), per-group flag barrier.
// History: R4 = best (3.1us/step): pipelined sc0sc1 b128 stage + wg barrier +
// tid0 dword flag + wave0 2-deep poll. R5-R10: every protocol/schedule change
// regressed or hung. Chain calibration (R4 vs R10): sync S~1.6us, compute
// C~1.5us per step.
// R11 (this): attack C only. Single-plane FP16 exchange+MFMA replaces the
// hi/lo bf16 split: fp16 weight rounding (2^-11 rel) beats bf16 (2^-9) so
// accuracy IMPROVES while MFMA count halves (64->32/wave), stage halves
// (4 b128/thread), unpack deleted, h-store 4B. Sync protocol byte-identical
// to R4.

#define Sv 256
#define Tv 32
#define Hv 512
#define KT 16          // k-tiles of 32 over K=512 (h only; x-part via P gather)
#define LDSA 520       // padded row stride in halfs (1040B = 65*16, b128-aligned)
#define GM 16          // batch rows per group

typedef _Float16 half8 __attribute__((ext_vector_type(8)));
typedef __attribute__((ext_vector_type(4))) float f32x4;
typedef __attribute__((ext_vector_type(4))) unsigned uint4v;

__device__ __forceinline__ float sigm(float x) { return 1.0f / (1.0f + __expf(-x)); }
__device__ __forceinline__ float tanh_fast(float x) {
  x = fminf(15.f, fmaxf(-15.f, x));
  float e = __expf(2.f * x);
  return (e - 1.f) / (e + 1.f);
}

// Coherent (device-scope) 16B load: bypasses L1/L2, pipelines like any vmem op.
__device__ __forceinline__ uint4v ld_b128_sys(const void* p) {
  uint4v r;
  asm volatile("global_load_dwordx4 %0, %1, off sc0 sc1" : "=v"(r) : "v"(p));
  return r;
}

// ---- P[v][n] = sum_k embed[v][k]*Wi[n][k] + be[n], fp32. 250 blocks x 4 tokens.
__global__ __launch_bounds__(256)
void build_P(const float* __restrict__ embed, const float* __restrict__ Wi,
             const float* __restrict__ be, float* __restrict__ P)
{
  __shared__ float ev[4][128];
  const int tid = threadIdx.x;
  const int v0  = blockIdx.x * 4;
#pragma unroll
  for (int i = 0; i < 2; ++i) {
    int e = tid + i * 256;
    ev[e >> 7][e & 127] = embed[(v0 + (e >> 7)) * 128 + (e & 127)];
  }
  __syncthreads();
#pragma unroll 1
  for (int cc = 0; cc < 8; ++cc) {
    int n = cc * 256 + tid;
    float b = be[n];
    float a0 = b, a1 = b, a2 = b, a3 = b;
    const f32x4* w = (const f32x4*)(Wi + n * 128);
#pragma unroll
    for (int k4 = 0; k4 < 32; ++k4) {
      f32x4 wv = w[k4];
#pragma unroll
      for (int j = 0; j < 4; ++j) {
        float wj = wv[j];
        int k = k4 * 4 + j;
        a0 += wj * ev[0][k]; a1 += wj * ev[1][k];
        a2 += wj * ev[2][k]; a3 += wj * ev[3][k];
      }
    }
    P[(size_t)(v0 + 0) * 2048 + n] = a0;
    P[(size_t)(v0 + 1) * 2048 + n] = a1;
    P[(size_t)(v0 + 2) * 2048 + n] = a2;
    P[(size_t)(v0 + 3) * 2048 + n] = a3;
  }
}

// hbuf: per group g, parity p: [16 rows][512 cols] fp16 = 16KB/parity.
// flags: per group, 16 dword flags in ONE 64B line.
__global__ __launch_bounds__(256, 1)
void lstm_enc(const int* __restrict__ enc_in, const float* __restrict__ P,
              const float* __restrict__ Wh,
              unsigned* __restrict__ flags, unsigned* __restrict__ hbuf,
              __half* __restrict__ enc_out)
{
  __shared__ __attribute__((aligned(16))) _Float16 Ah[GM][LDSA];
  __shared__ float zbuf[4][GM][37];

  const int tid  = threadIdx.x;
  const int wg   = blockIdx.x;
  const int g    = wg & 15;   // group (members share wg%8 -> same XCD heuristically; perf only)
  const int cb   = wg >> 4;   // column block: owns z-cols [q*512 + cb*32, +32) per gate q
  const int wave = tid >> 6;  // wave == gate q (0=i,1=f,2=g,3=o)
  const int lane = tid & 63;
  const int m16  = lane & 15;
  const int qd   = lane >> 4;

  // ---- Wh fragments in registers (fp16): lane holds W'[n][k] for
  // n = wave*512 + cb*32 + nt*16 + m16, k = kt*32 + qd*8 + j (j=0..7).
  half8 wf[KT][2];
#pragma unroll
  for (int kt = 0; kt < KT; ++kt) {
#pragma unroll
    for (int nt = 0; nt < 2; ++nt) {
      int n  = wave * 512 + cb * 32 + nt * 16 + m16;
      int k0 = kt * 32 + qd * 8;
      const float* src = Wh + (size_t)n * Hv + k0;
      f32x4 f0 = *(const f32x4*)(src);
      f32x4 f1 = *(const f32x4*)(src + 4);
      half8 w;
      w[0] = (_Float16)f0[0]; w[1] = (_Float16)f0[1];
      w[2] = (_Float16)f0[2]; w[3] = (_Float16)f0[3];
      w[4] = (_Float16)f1[0]; w[5] = (_Float16)f1[1];
      w[6] = (_Float16)f1[2]; w[7] = (_Float16)f1[3];
      wf[kt][nt] = w;
    }
  }

  // gates-phase mapping: thread owns (row gr, cols gj, gj+1); c-state in regs
  const int gr = tid >> 4;
  const int gj = (tid & 15) * 2;
  float c0 = 0.f, c1 = 0.f;

  unsigned* hb_g = hbuf + (size_t)g * (2 * GM * Hv / 2);   // dwords: 2 parities x 4096
  unsigned* flg  = flags + g * 16;

  // ---- P prefetch for s=0 (acc-layout rows r0..r0+3, cols ncol, ncol+16)
  const int r0   = qd * 4;
  const int ncol = wave * 512 + cb * 32 + m16;
  float px0[4], px1[4];
#pragma unroll
  for (int rr = 0; rr < 4; ++rr) {
    int tk  = enc_in[(g * GM + r0 + rr) * Sv + 0];
    px0[rr] = P[(size_t)tk * 2048 + ncol];
    px1[rr] = P[(size_t)tk * 2048 + ncol + 16];
  }

#pragma unroll 1
  for (int s = 0; s < Sv; ++s) {
    const int p = s & 1;

    // ---- stage h (parity p): 4 pipelined coherent b128 loads -> direct LDS
    // (fragment-native fp16 layout; zero unpack).
    {
      const char* hsrc = (const char*)(hb_g + (size_t)p * 4096);
      uint4v r4[4];
#pragma unroll
      for (int j = 0; j < 4; ++j)
        r4[j] = ld_b128_sys(hsrc + j * 4096 + tid * 16);
      asm volatile("s_waitcnt vmcnt(0)"
                   : "+v"(r4[0]), "+v"(r4[1]), "+v"(r4[2]), "+v"(r4[3])
                   :: "memory");
      const int colh = (tid & 63) * 8;        // half index within row
      const int rw   = tid >> 6;              // wave id -> row offset
#pragma unroll
      for (int j = 0; j < 4; ++j) {
        int row = j * 4 + rw;
        *(uint4v*)&Ah[row][colh] = r4[j];
      }
    }
    __syncthreads();   // B1: stage complete

    // ---- MFMA: z_h = A @ Wh^T (fp16 inputs, fp32 accumulate)
    f32x4 acc0 = {0.f, 0.f, 0.f, 0.f};
    f32x4 acc1 = {0.f, 0.f, 0.f, 0.f};
#pragma unroll
    for (int kt = 0; kt < KT; ++kt) {
      half8 a = *(const half8*)&Ah[m16][kt * 32 + qd * 8];
      acc0 = __builtin_amdgcn_mfma_f32_16x16x32_f16(a, wf[kt][0], acc0, 0, 0, 0);
      acc1 = __builtin_amdgcn_mfma_f32_16x16x32_f16(a, wf[kt][1], acc1, 0, 0, 0);
    }
    // C/D layout: col = lane&15, row = (lane>>4)*4 + reg; add fp32 x-part (P)
#pragma unroll
    for (int rr = 0; rr < 4; ++rr) {
      zbuf[wave][r0 + rr][m16]      = acc0[rr] + px0[rr];
      zbuf[wave][r0 + rr][16 + m16] = acc1[rr] + px1[rr];
    }
    __syncthreads();   // B2: zbuf complete (also fences Ah reads vs next stage writes)

    // ---- gates for (gr, gj), (gr, gj+1)
    float i0 = zbuf[0][gr][gj], i1 = zbuf[0][gr][gj + 1];
    float f0g = zbuf[1][gr][gj], f1g = zbuf[1][gr][gj + 1];
    float g0 = zbuf[2][gr][gj], g1 = zbuf[2][gr][gj + 1];
    float o0 = zbuf[3][gr][gj], o1 = zbuf[3][gr][gj + 1];
    float cn0 = sigm(f0g) * c0 + sigm(i0) * tanh_fast(g0);
    float cn1 = sigm(f1g) * c1 + sigm(i1) * tanh_fast(g1);
    float hn0 = sigm(o0) * tanh_fast(cn0);
    float hn1 = sigm(o1) * tanh_fast(cn1);
    c0 = cn0; c1 = cn1;

    // ---- h store: ONE coalesced 4B agent-scope store per thread (2 fp16)
    __half2 h2;
    h2.x = __float2half(hn0);
    h2.y = __float2half(hn1);
    {
      unsigned pk = __builtin_bit_cast(unsigned, h2);
      // dword index within parity: (row*512 + col)/2
      __hip_atomic_store(
          hb_g + (size_t)(p ^ 1) * 4096 + gr * 256 + (cb * 32 + gj) / 2,
          pk, __ATOMIC_RELAXED, __HIP_MEMORY_SCOPE_AGENT);
    }

    if (s + 1 < Sv) {
      // ---- B3: wg-wide barrier (drains vmcnt(0) -> all 256 h stores acked
      // at device scope), then ONE dword flag.
      __syncthreads();
      if (tid == 0)
        __hip_atomic_store(&flg[cb], (unsigned)(s + 1),
                           __ATOMIC_RELAXED, __HIP_MEMORY_SCOPE_AGENT);

      // enc_out fp16 pair + next-step P gather: issued under the poll window
      *(__half2*)(enc_out + ((size_t)(g * GM + gr) * Sv + s) * Hv + cb * 32 + gj) = h2;
      {
        int sn = s + 1;
#pragma unroll
        for (int rr = 0; rr < 4; ++rr) {
          int tk  = enc_in[(g * GM + r0 + rr) * Sv + sn];
          px0[rr] = P[(size_t)tk * 2048 + ncol];
          px1[rr] = P[(size_t)tk * 2048 + ncol + 16];
        }
      }

      // ---- wave0 2-deep pipelined poll of the group's 16 dword flags (R4 asm)
      if (wave == 0) {
        const unsigned* fp = &flg[lane & 15];
        unsigned tgt = (unsigned)(s + 1);
        unsigned fa = 0, fb = 0;
        asm volatile(
          "global_load_dword %0, %2, off sc0 sc1\n\t"
          "global_load_dword %1, %2, off sc0 sc1\n\t"
          "1:\n\t"
          "s_waitcnt vmcnt(1)\n\t"
          "v_cmp_lt_u32 vcc, %0, %3\n\t"
          "s_cbranch_vccz 2f\n\t"
          "global_load_dword %0, %2, off sc0 sc1\n\t"
          "s_waitcnt vmcnt(1)\n\t"
          "v_cmp_lt_u32 vcc, %1, %3\n\t"
          "s_cbranch_vccz 2f\n\t"
          "global_load_dword %1, %2, off sc0 sc1\n\t"
          "s_branch 1b\n\t"
          "2:\n\t"
          "s_waitcnt vmcnt(0)\n\t"
          : "+v"(fa), "+v"(fb)
          : "v"(fp), "v"(tgt)
          : "vcc", "memory");
      }
      __syncthreads();   // B4: group step confirmed
    } else {
      // last step: just write enc_out
      *(__half2*)(enc_out + ((size_t)(g * GM + gr) * Sv + s) * Hv + cb * 32 + gj) = h2;
    }
  }
}

// One wg per batch row: scores = enc_out[b] @ We, softmax over S, ctx, then
// pa/pt dots tiled over T. fp32 math, fp16 enc_out reads (16B score loads).
__global__ __launch_bounds__(256)
void attn_out(const __half* __restrict__ enc_out, const float* __restrict__ Wf,
              const float* __restrict__ Wa, const float* __restrict__ ba,
              const float* __restrict__ Wt, const float* __restrict__ bt,
              float* __restrict__ out)
{
  __shared__ float We[512];
  __shared__ float sc[256];
  __shared__ float ctx[512];
  __shared__ float red[8];
  const int tid = threadIdx.x;
  const int b   = blockIdx.x;
  const int wv  = tid >> 6;
  const int ln  = tid & 63;

  We[tid] = Wf[tid];
  We[tid + 256] = Wf[tid + 256];
  __syncthreads();

  const uint4* r4 = (const uint4*)(enc_out + ((size_t)b * Sv + tid) * Hv);
  float a = 0.f;
#pragma unroll 4
  for (int k = 0; k < 64; ++k) {
    uint4 v = r4[k];
    float2 f0 = __half22float2(__builtin_bit_cast(__half2, v.x));
    float2 f1 = __half22float2(__builtin_bit_cast(__half2, v.y));
    float2 f2 = __half22float2(__builtin_bit_cast(__half2, v.z));
    float2 f3 = __half22float2(__builtin_bit_cast(__half2, v.w));
    const float* wp = &We[8 * k];
    a += f0.x * wp[0] + f0.y * wp[1] + f1.x * wp[2] + f1.y * wp[3]
       + f2.x * wp[4] + f2.y * wp[5] + f3.x * wp[6] + f3.y * wp[7];
  }

  float m = a;
  for (int off = 32; off; off >>= 1) m = fmaxf(m, __shfl_down(m, off));
  if (ln == 0) red[wv] = m;
  __syncthreads();
  if (tid == 0) red[4] = fmaxf(fmaxf(red[0], red[1]), fmaxf(red[2], red[3]));
  __syncthreads();
  float e = __expf(a - red[4]);
  float ssum = e;
  for (int off = 32; off; off >>= 1) ssum += __shfl_down(ssum, off);
  if (ln == 0) red[wv] = ssum;
  __syncthreads();
  if (tid == 0) red[5] = red[0] + red[1] + red[2] + red[3];
  __syncthreads();
  sc[tid] = e * (1.f / red[5]);
  __syncthreads();

  {
    float a0 = 0.f, a1 = 0.f;
    const __half2* base = (const __half2*)(enc_out + (size_t)b * Sv * Hv) + tid;
#pragma unroll 4
    for (int s2 = 0; s2 < Sv; ++s2) {
      float2 f = __half22float2(base[s2 * (Hv / 2)]);
      float w = sc[s2];
      a0 += w * f.x;
      a1 += w * f.y;
    }
    ctx[2 * tid] = a0;
    ctx[2 * tid + 1] = a1;
  }
  __syncthreads();

  if (tid < 88) {
    const float* wr = (tid < 8) ? (Wa + tid * Hv) : (Wt + (tid - 8) * Hv);
    float o = (tid < 8) ? ba[tid] : bt[tid - 8];
    for (int k = 0; k < Hv; ++k) o += ctx[k] * wr[k];
    if (tid < 8) {
      float* o0 = out + (size_t)b * Tv * 8;
#pragma unroll
      for (int t = 0; t < Tv; ++t) o0[t * 8 + tid] = o;
    } else {
      int n = tid - 8;
      float* o1 = out + 65536 + (size_t)b * Tv * 80;
#pragma unroll
      for (int t = 0; t < Tv; ++t) o1[t * 80 + n] = o;
    }
  }
}

extern "C" void kernel_launch(void* const* d_in, const int* in_sizes, int n_in,
                              void* d_out, int out_size, void* d_ws, size_t ws_size,
                              hipStream_t stream)
{
  (void)in_sizes; (void)n_in; (void)out_size; (void)ws_size;
  const int*   enc_in = (const int*)d_in[0];
  const float* embed  = (const float*)d_in[2];
  const float* Wi     = (const float*)d_in[3];
  const float* Wh     = (const float*)d_in[4];
  const float* be     = (const float*)d_in[5];
  const float* Wa     = (const float*)d_in[11];
  const float* ba     = (const float*)d_in[12];
  const float* Wt     = (const float*)d_in[13];
  const float* bt     = (const float*)d_in[14];
  const float* Wf     = (const float*)d_in[15];
  // d_in[1] decoder_target, [6..10] decoder weights, [16] bf: dead code

  char* ws = (char*)d_ws;
  unsigned* flags  = (unsigned*)ws;                          // 16 groups x 64B = 1KB (4KB reserved)
  unsigned* hbuf   = (unsigned*)(ws + 4096);                 // 16 x 2 x 16KB fp16 = 512KB
  float*    P      = (float*)(ws + 4096 + (512u << 10));     // 1000 x 2048 fp32 = 8MB
  __half*   encout = (__half*)(ws + 4096 + (512u << 10) + (8u << 20)); // 64MB

  hipMemsetAsync(d_ws, 0, 4096 + (512u << 10), stream);      // zero flags + h0

  build_P<<<dim3(250), dim3(256), 0, stream>>>(embed, Wi, be, P);
  lstm_enc<<<dim3(256), dim3(256), 0, stream>>>(enc_in, P, Wh, flags, hbuf, encout);
  attn_out<<<dim3(256), dim3(256), 0, stream>>>(encout, Wf, Wa, ba, Wt, bt, (float*)d_out);
}